// Round 8
// baseline (441.854 us; speedup 1.0000x reference)
//
#include <hip/hip_runtime.h>
#include <cstdint>
#include <cstddef>

using bf16x8 = __attribute__((ext_vector_type(8))) short;
using f32x4  = __attribute__((ext_vector_type(4))) float;

__device__ __forceinline__ unsigned short f2bf(float f) {
  unsigned int u = __builtin_bit_cast(unsigned int, f);
  u += 0x7FFFu + ((u >> 16) & 1u);   // round-to-nearest-even
  return (unsigned short)(u >> 16);
}

__device__ __forceinline__ void gl_lds16(const void* g, void* l) {
  __builtin_amdgcn_global_load_lds(
      (const __attribute__((address_space(1))) unsigned int*)g,
      (__attribute__((address_space(3))) unsigned int*)l,
      16, 0, 0);
}

#define MFMA  __builtin_amdgcn_mfma_f32_16x16x32_bf16
#define MFMA8 __builtin_amdgcn_mfma_f32_16x16x32_fp8_fp8

// ============ fused QK+exp+PV kernel ======================================
// Eliminates the 64MB E write + 64MB E re-read + the PV kernel's convoy
// exposure (R7: f8 67.5us + PV ~60us for ~45us of per-CU resources).
// Per block (256 thr, 4 waves): m-tile 64, n-chunk 1024 (4 n-splits), e=512
// in registers (acc 128 f32/thread -> ~230 VGPR -> 2 waves/SIMD -> 2 blk/CU).
// Grid 512 = exactly 2/CU, one generation. n-split pinned to XCD pair so the
// 1MB v2T slice + 0.5MB p-slice + 2MB x-slice stay L2-resident.
// LDS 80KB: pool 64KB = slotA[0,32K) | slotB[32K,64K); QK uses 12KB prefixes
// (x 4K + p 8K), PV v2T slots use full 32K halves; E-tile 16KB at 64K.
// Per n-tile (128 n): 8 QK convoys (fp8 BK=64, 16 MFMA/wave, vmcnt(3)) ->
// exp epilogue (PV sub0 flying underneath) -> 4 PV convoys (n-sub 32,
// 32 MFMA/wave, vmcnt(8)). Cross-phase prefetch keeps loads in flight across
// every barrier except the one epilogue drain.
// Swizzles (bank-verified 2-way = free):
//  - QK x/p slots: 64B rows, phys 16B slot q holds global chunk q^((r>>2)&3)
//    (R6/R7-proven for b64 reads).
//  - v2T slots: 64B rows, s(r)=(r>>1)&3 -- (r&1, q^s) bijective over 16 lanes
//    for b128 reads. (R6's (r>>2)&3 was a 4-way conflict for b128.)
//  - E-tile: 128-col rows, 16B chunk ch stored at ch^(r&7); free for both
//    the 2B epilogue writes and the b128 PV reads.
__global__ __launch_bounds__(256, 2)
void fused_qkpv(const unsigned char* __restrict__ Xq,    // [8192][512] fp8
                const unsigned char* __restrict__ Pq,    // [4096][512] fp8
                const unsigned short* __restrict__ V2T,  // [512][4096] bf16
                const float* __restrict__ x2g,
                const float* __restrict__ p2g,
                const float* __restrict__ scg,
                float* __restrict__ denom,               // [8192], pre-zeroed
                float* __restrict__ Pout)                // [4][8192][512] f32
{
  __shared__ unsigned char smem[81920];
  unsigned short* Es = (unsigned short*)(smem + 65536);  // 64 x 128 bf16, swz

  const int tid  = threadIdx.x;
  const int lane = tid & 63;
  const int wv   = tid >> 6;
  const int l16  = lane & 15;
  const int quad = lane >> 4;

  // 512 blocks: XCD pair {2s,2s+1} owns n-split s; parity picks m half.
  const int lin    = blockIdx.x;
  const int xcd    = lin & 7;
  const int nsplit = xcd >> 1;
  const int mt     = (xcd & 1) * 64 + (lin >> 3);   // [0,128)
  const int m0     = mt * 64;
  const int nch    = nsplit * 1024;

  // ---- staging address bases ----
  const unsigned char* gx; int lx;                  // x: 1 load/thread
  {
    const int c = tid, row = c >> 2;                // row in [0,64)
    gx = Xq + (size_t)(m0 + row) * 512 + (((c & 3) ^ ((row >> 2) & 3)) * 16);
    lx = c * 16;
  }
  const unsigned char* gp0;                          // p: 2 loads/thread
  {
    const int c = tid, row = c >> 2;                // rows [0,64); +64 same swz
    gp0 = Pq + (size_t)(nch + row) * 512 + (((c & 3) ^ ((row >> 2) & 3)) * 16);
  }
  const unsigned short* gv0;                         // v2T: 8 loads/thread
  {
    const int c = tid, row = c >> 2;                // rows [0,64); +64k same swz
    gv0 = V2T + (size_t)row * 4096 + nch + (((c & 3) ^ ((row >> 1) & 3)) * 8);
  }

  auto issue_qk = [&](unsigned char* S, int ntOffB, int kc) {
    gl_lds16(gx + kc, S + lx);
    gl_lds16(gp0 + ntOffB + kc, S + 4096 + tid * 16);
    gl_lds16(gp0 + 32768 + ntOffB + kc, S + 8192 + tid * 16);
  };
  auto issue_pv = [&](unsigned char* S, int nOff) {   // nOff in shorts
#pragma unroll
    for (int i = 0; i < 8; ++i)
      gl_lds16(gv0 + (size_t)i * 262144 + nOff, S + tid * 16 + i * 4096);
  };

  f32x4 acc[4][8];
#pragma unroll
  for (int i = 0; i < 4; ++i)
#pragma unroll
    for (int j = 0; j < 8; ++j) {
      f32x4 z = {0.f, 0.f, 0.f, 0.f};
      acc[i][j] = z;
    }

  issue_qk(smem + 32768, 0, 0);                      // nt0 it0 -> B prefix

#pragma unroll 1
  for (int nt = 0; nt < 8; ++nt) {
    const int ntOffB = nt * 65536;                   // p bytes per n-tile

    // ---- QK: C[64x128] over K=512, fp8, 8 convoys ----
    f32x4 cacc[4][2];
#pragma unroll
    for (int i = 0; i < 4; ++i)
#pragma unroll
      for (int j = 0; j < 2; ++j) {
        f32x4 z = {0.f, 0.f, 0.f, 0.f};
        cacc[i][j] = z;
      }
#pragma unroll
    for (int it = 0; it < 8; ++it) {
      __builtin_amdgcn_s_barrier();
      if (it < 7) {
        issue_qk((it & 1) ? smem + 32768 : smem, ntOffB, (it + 1) * 64);
        __builtin_amdgcn_s_waitcnt(0x0F73);          // my 3 landed; next flying
      } else {
        issue_pv(smem + 32768, nt * 128);            // PV sub0 -> B full
        __builtin_amdgcn_s_waitcnt(0x0F78);          // my 3 landed; 8 PV flying
      }
      __builtin_amdgcn_s_barrier();
      {
        const unsigned char* As = (it & 1) ? smem : smem + 32768;
        const unsigned char* Bs = As + 4096;
        __builtin_amdgcn_s_setprio(1);
#pragma unroll
        for (int sub = 0; sub < 2; ++sub) {
          long af[4], bq[2];
#pragma unroll
          for (int mi = 0; mi < 4; ++mi) {
            const int r = mi * 16 + l16;
            af[mi] = *(const long*)&As[r * 64 +
                       (((sub * 2 + (quad >> 1)) ^ ((r >> 2) & 3)) * 16) + (quad & 1) * 8];
          }
#pragma unroll
          for (int ni = 0; ni < 2; ++ni) {
            const int r = wv * 32 + ni * 16 + l16;
            bq[ni] = *(const long*)&Bs[r * 64 +
                       (((sub * 2 + (quad >> 1)) ^ ((r >> 2) & 3)) * 16) + (quad & 1) * 8];
          }
#pragma unroll
          for (int mi = 0; mi < 4; ++mi)
#pragma unroll
            for (int ni = 0; ni < 2; ++ni)
              cacc[mi][ni] = MFMA8(af[mi], bq[ni], cacc[mi][ni], 0, 0, 0);
        }
        __builtin_amdgcn_s_setprio(0);
      }
    }

    // ---- epilogue: E = exp(scale/(dist+0.1)) -> swizzled LDS; denom ----
    {
      float p2v[2], scv[2];
#pragma unroll
      for (int ni = 0; ni < 2; ++ni) {
        const int n = nch + nt * 128 + wv * 32 + ni * 16 + l16;
        p2v[ni] = p2g[n];
        scv[ni] = scg[n] * 1.44269504088896f;        // fold log2(e)
      }
#pragma unroll
      for (int mi = 0; mi < 4; ++mi) {
#pragma unroll
        for (int rr = 0; rr < 4; ++rr) {
          const int row = mi * 16 + quad * 4 + rr;
          const float rowa = x2g[m0 + row];
          float s = 0.f;
#pragma unroll
          for (int ni = 0; ni < 2; ++ni) {
            const int col = wv * 32 + ni * 16 + l16;
            const float v = cacc[mi][ni][rr];
            float sq   = fmaxf(rowa - 2.0f * v + p2v[ni], 0.0f);
            float dist = __builtin_amdgcn_sqrtf(sq);
            float e    = __builtin_amdgcn_exp2f(scv[ni] * __builtin_amdgcn_rcpf(dist + 0.1f));
            const int ch = col >> 3;
            Es[row * 128 + ((ch ^ (row & 7)) * 8) + (col & 7)] = f2bf(e);
            s += e;
          }
          s += __shfl_down(s, 8);
          s += __shfl_down(s, 4);
          s += __shfl_down(s, 2);
          s += __shfl_down(s, 1);
          if (l16 == 0) unsafeAtomicAdd(&denom[m0 + row], s);
        }
      }
    }
    __builtin_amdgcn_s_waitcnt(0x0070);              // E visible; sub0 landed
    __builtin_amdgcn_s_barrier();

    // ---- PV: acc[64 x 512] += E . v2T^T, 4 convoys of n-sub 32 ----
#pragma unroll
    for (int q = 0; q < 4; ++q) {
      if (q) __builtin_amdgcn_s_barrier();
      if (q < 3) {
        issue_pv((q & 1) ? smem + 32768 : smem, nt * 128 + (q + 1) * 32);
        __builtin_amdgcn_s_waitcnt(0x0F78);          // sub q landed; q+1 flying
      } else if (nt < 7) {
        issue_qk(smem + 32768, ntOffB + 65536, 0);   // next nt it0 -> B prefix
        __builtin_amdgcn_s_waitcnt(0x0F73);          // sub3 landed; QK flying
      } else {
        __builtin_amdgcn_s_waitcnt(0x0F70);
      }
      __builtin_amdgcn_s_barrier();
      {
        const unsigned short* Vs =
            (const unsigned short*)((q & 1) ? smem : smem + 32768);
        bf16x8 af[4], bfr[8];
#pragma unroll
        for (int mi = 0; mi < 4; ++mi) {
          const int r = mi * 16 + l16;
          af[mi] = *(const bf16x8*)&Es[r * 128 + (((q * 4 + quad) ^ (r & 7)) * 8)];
        }
#pragma unroll
        for (int ei = 0; ei < 8; ++ei) {
          const int er = wv * 128 + ei * 16 + l16;
          bfr[ei] = *(const bf16x8*)&Vs[er * 32 + ((quad ^ ((er >> 1) & 3)) * 8)];
        }
        __builtin_amdgcn_s_setprio(1);
#pragma unroll
        for (int mi = 0; mi < 4; ++mi)
#pragma unroll
          for (int ei = 0; ei < 8; ++ei)
            acc[mi][ei] = MFMA(af[mi], bfr[ei], acc[mi][ei], 0, 0, 0);
        __builtin_amdgcn_s_setprio(0);
      }
    }
  }

  // ---- store fp32 partial for this n-split ----
  float* P = Pout + (size_t)nsplit * (8192ull * 512);
#pragma unroll
  for (int mi = 0; mi < 4; ++mi) {
#pragma unroll
    for (int rr = 0; rr < 4; ++rr) {
      const int m = m0 + mi * 16 + quad * 4 + rr;
#pragma unroll
      for (int ei = 0; ei < 8; ++ei)
        P[(size_t)m * 512 + wv * 128 + ei * 16 + l16] = acc[mi][ei][rr];
    }
  }
}

// ============ 64x64-tile GEMM for the two small 512-K GEMMs ================
__global__ __launch_bounds__(256, 4)
void gemm64(const unsigned short* __restrict__ A,
            const unsigned short* __restrict__ B,
            unsigned short* __restrict__ C,
            int M, int N, int K)
{
  constexpr int ASZ = 64 * 64;    // shorts per slot (8 KB)
  __shared__ unsigned short smem[4 * ASZ];    // A0 A1 B0 B1 = 32 KB
  unsigned short* As = smem;
  unsigned short* Bs = smem + 2 * ASZ;

  const int tid  = threadIdx.x;
  const int lane = tid & 63;
  const int wv   = tid >> 6;
  const int l16  = lane & 15;
  const int quad = lane >> 4;

  const int n0 = blockIdx.x * 64;
  const int m0 = blockIdx.y * 64;

  f32x4 acc[4];
#pragma unroll
  for (int i = 0; i < 4; ++i) {
    f32x4 z = {0.f, 0.f, 0.f, 0.f};
    acc[i] = z;
  }

  const unsigned short* gA[2]; const unsigned short* gB[2]; int lc[2];
#pragma unroll
  for (int i = 0; i < 2; ++i) {
    const int c = tid + i * 256;
    const int row = c >> 3, col = ((c & 7) ^ (row & 7)) * 8;
    gA[i] = A + (size_t)(m0 + row) * K + col;
    gB[i] = B + (size_t)(n0 + row) * K + col;
    lc[i] = c * 8;
  }

  auto issue = [&](int st, int kc) {
#pragma unroll
    for (int i = 0; i < 2; ++i) gl_lds16(gA[i] + kc, &As[st * ASZ + lc[i]]);
#pragma unroll
    for (int i = 0; i < 2; ++i) gl_lds16(gB[i] + kc, &Bs[st * ASZ + lc[i]]);
  };

  const int nk = K >> 6;
  issue(0, 0);
  int cur = 0;
#pragma unroll 1
  for (int it = 0; it < nk; ++it) {
    __builtin_amdgcn_s_barrier();
    if (it + 1 < nk) {
      issue(cur ^ 1, (it + 1) << 6);
      __builtin_amdgcn_s_waitcnt(0x0F74);
    } else {
      __builtin_amdgcn_s_waitcnt(0x0F70);
    }
    __builtin_amdgcn_s_barrier();

#pragma unroll
    for (int ks = 0; ks < 2; ++ks) {
      bf16x8 af[4], bfr;
#pragma unroll
      for (int mi = 0; mi < 4; ++mi) {
        const int r = mi * 16 + l16;
        af[mi] = *(const bf16x8*)&As[cur * ASZ + r * 64 + (((ks * 4 + quad) ^ (r & 7)) * 8)];
      }
      {
        const int r = wv * 16 + l16;
        bfr = *(const bf16x8*)&Bs[cur * ASZ + r * 64 + (((ks * 4 + quad) ^ (r & 7)) * 8)];
      }
#pragma unroll
      for (int mi = 0; mi < 4; ++mi)
        acc[mi] = MFMA(af[mi], bfr, acc[mi], 0, 0, 0);
    }
    cur ^= 1;
  }

#pragma unroll
  for (int mi = 0; mi < 4; ++mi) {
#pragma unroll
    for (int r = 0; r < 4; ++r) {
      const int m = m0 + mi * 16 + quad * 4 + r;
      const int n = n0 + wv * 16 + l16;
      C[(size_t)m * N + n] = f2bf(acc[mi][r]);
    }
  }
}

// ===== prep_all: conversions/norms/bias in ONE launch (3456 blocks) =====
__global__ void prep_all(const float* __restrict__ x, const float* __restrict__ positions,
                         const float* __restrict__ w_v, const float* __restrict__ w_o,
                         const float* __restrict__ b_v, const float* __restrict__ b_o,
                         unsigned char* __restrict__ xq, unsigned char* __restrict__ pq,
                         unsigned short* __restrict__ pb,
                         unsigned short* __restrict__ wvb, unsigned short* __restrict__ wob,
                         float* __restrict__ x2, float* __restrict__ p2,
                         float* __restrict__ bias2, float* __restrict__ denom)
{
  const int b = blockIdx.x;
  const int tid = threadIdx.x;
  const int lane = tid & 63;
  const int wv = tid >> 6;

  if (b < 3072) {
    const bool isx = (b < 2048);
    const int r = (isx ? b : b - 2048) * 4 + wv;
    const float* X = isx ? x : positions;
    const float4* row = (const float4*)(X + (size_t)r * 512);
    const float4 a = row[lane];
    const float4 c = row[lane + 64];
    int wa = __builtin_amdgcn_cvt_pk_fp8_f32(a.x, a.y, 0, false);
    wa = __builtin_amdgcn_cvt_pk_fp8_f32(a.z, a.w, wa, true);
    int wc = __builtin_amdgcn_cvt_pk_fp8_f32(c.x, c.y, 0, false);
    wc = __builtin_amdgcn_cvt_pk_fp8_f32(c.z, c.w, wc, true);
    unsigned int* Q = (unsigned int*)(isx ? xq : pq) + (size_t)r * 128;
    Q[lane] = (unsigned int)wa;
    Q[lane + 64] = (unsigned int)wc;
    if (!isx) {
      ushort4 ua, uc;
      ua.x = f2bf(a.x); ua.y = f2bf(a.y); ua.z = f2bf(a.z); ua.w = f2bf(a.w);
      uc.x = f2bf(c.x); uc.y = f2bf(c.y); uc.z = f2bf(c.z); uc.w = f2bf(c.w);
      ushort4* orow = (ushort4*)(pb + (size_t)r * 512);
      orow[lane] = ua;
      orow[lane + 64] = uc;
    }
    float s = a.x*a.x + a.y*a.y + a.z*a.z + a.w*a.w
            + c.x*c.x + c.y*c.y + c.z*c.z + c.w*c.w;
#pragma unroll
    for (int off = 32; off > 0; off >>= 1) s += __shfl_down(s, off, 64);
    if (lane == 0) {
      if (isx) { x2[r] = s; denom[r] = 0.f; }
      else     { p2[r] = s; }
    }
  } else if (b < 3328) {
    const int i = (b - 3072) * 256 + tid;
    float4 a = ((const float4*)w_v)[i];
    float4 c = ((const float4*)w_o)[i];
    ushort4 ua, uc;
    ua.x = f2bf(a.x); ua.y = f2bf(a.y); ua.z = f2bf(a.z); ua.w = f2bf(a.w);
    uc.x = f2bf(c.x); uc.y = f2bf(c.y); uc.z = f2bf(c.z); uc.w = f2bf(c.w);
    ((ushort4*)wvb)[i] = ua;
    ((ushort4*)wob)[i] = uc;
  } else {
    const int e = (b - 3328) * 4 + wv;
    float s = 0.f;
#pragma unroll
    for (int j = 0; j < 8; ++j)
      s += w_o[(size_t)e * 512 + lane + j * 64] * b_v[lane + j * 64];
#pragma unroll
    for (int off = 32; off > 0; off >>= 1) s += __shfl_down(s, off, 64);
    if (lane == 0) bias2[e] = b_o[e] + s;   // softmax rows sum to 1
  }
}

// out[m,e] = (P0+P1+P2+P3)[m,e]/denom[m] + bias2[e]   (P fp32 partials)
__global__ void reduce_out4(const float* __restrict__ P,
                            const float* __restrict__ denom,
                            const float* __restrict__ bias2,
                            float* __restrict__ out) {
  const int i = blockIdx.x * 256 + threadIdx.x;   // 1,048,576 float4s
  const int m = i >> 7;
  const float rd = 1.0f / denom[m];
  const float4 b4 = ((const float4*)bias2)[i & 127];
  const float4* PP = (const float4*)P;
  const float4 a = PP[i];
  const float4 b = PP[i + 1048576];
  const float4 c = PP[i + 2097152];
  const float4 d = PP[i + 3145728];
  float4 o;
  o.x = (a.x + b.x + c.x + d.x) * rd + b4.x;
  o.y = (a.y + b.y + c.y + d.y) * rd + b4.y;
  o.z = (a.z + b.z + c.z + d.z) * rd + b4.z;
  o.w = (a.w + b.w + c.w + d.w) * rd + b4.w;
  ((float4*)out)[i] = o;
}

extern "C" void kernel_launch(void* const* d_in, const int* in_sizes, int n_in,
                              void* d_out, int out_size, void* d_ws, size_t ws_size,
                              hipStream_t stream) {
  const float* x         = (const float*)d_in[0];
  const float* positions = (const float*)d_in[1];
  const float* scale     = (const float*)d_in[2];
  const float* w_v       = (const float*)d_in[3];
  const float* b_v       = (const float*)d_in[4];
  const float* w_o       = (const float*)d_in[5];
  const float* b_o       = (const float*)d_in[6];
  float* out = (float*)d_out;

  char* base = (char*)d_ws;
  float*          P4    = (float*)(base + 0);                 // 64 MB [fused..reduce]
  unsigned short* val   = (unsigned short*)(base + 0);        // 4 MB, parks in P4
  unsigned short* v2T   = (unsigned short*)(base + 67108864); // 4 MB
  float*          denom = (float*)(base + 71303168);          // 32 KB
  float*          x2    = (float*)(base + 71335936);          // 32 KB
  float*          p2    = (float*)(base + 71368704);          // 16 KB
  float*          bias2 = (float*)(base + 71385088);          // 2 KB
  char* base2 = base + 71387136;
  unsigned char*  xq    = (unsigned char*)base2;              // 4 MB  [prep..fused]
  unsigned char*  pq    = (unsigned char*)(base2 + 4194304);  // 2 MB  [prep..fused]
  unsigned short* pb    = (unsigned short*)(base2 + 6291456); // 4 MB  [prep..val]
  unsigned short* wvb   = (unsigned short*)(base2 + 10485760);// 0.5 MB
  unsigned short* wo_b  = (unsigned short*)(base2 + 11010048);// 0.5 MB

  // all prep in one launch
  prep_all<<<3456, 256, 0, stream>>>(x, positions, w_v, w_o, b_v, b_o,
                                     xq, pq, pb, wvb, wo_b, x2, p2, bias2, denom);

  // val[n,d] = sum_k p[n,k] wv[d,k]   (512 blocks of 64x64)
  gemm64<<<dim3(8, 64), 256, 0, stream>>>(pb, wvb, val, 4096, 512, 512);

  // v2T[e,n] = sum_d wo[e,d] val[n,d]   (512 blocks of 64x64)
  gemm64<<<dim3(64, 8), 256, 0, stream>>>(wo_b, val, v2T, 512, 4096, 512);

  // fused: QK (fp8) + exp + PV, fp32 partials + denom atomics
  fused_qkpv<<<512, 256, 0, stream>>>(xq, pq, v2T, x2, p2, scale, denom, P4);

  // out = (P0+P1+P2+P3)/denom + bias2
  reduce_out4<<<4096, 256, 0, stream>>>(P4, denom, bias2, out);
}

// Round 9
// 221.402 us; speedup vs baseline: 1.9957x; 1.9957x over previous
//
#include <hip/hip_runtime.h>
#include <cstdint>
#include <cstddef>

using bf16x8 = __attribute__((ext_vector_type(8))) short;
using f32x4  = __attribute__((ext_vector_type(4))) float;

__device__ __forceinline__ unsigned short f2bf(float f) {
  unsigned int u = __builtin_bit_cast(unsigned int, f);
  u += 0x7FFFu + ((u >> 16) & 1u);   // round-to-nearest-even
  return (unsigned short)(u >> 16);
}
__device__ __forceinline__ float bf2f(unsigned int h16) {
  unsigned int u = h16 << 16;
  return __builtin_bit_cast(float, u);
}

__device__ __forceinline__ void gl_lds16(const void* g, void* l) {
  __builtin_amdgcn_global_load_lds(
      (const __attribute__((address_space(1))) unsigned int*)g,
      (__attribute__((address_space(3))) unsigned int*)l,
      16, 0, 0);
}

#define MFMA  __builtin_amdgcn_mfma_f32_16x16x32_bf16
#define MFMA8 __builtin_amdgcn_mfma_f32_16x16x32_fp8_fp8

// ============ merged launch 2: fp8 E-kernel (2048 blocks) + v2T GEMM (512) =
// f8 path: R7-proven. BK=64 fp8, 3-slot distance-2 counted vmcnt, 48KB LDS,
//   3 blk/CU. E=exp(scale/(dist+0.1)) epilogue + denom atomics.
// v2T path: v2T[e,n] = sum_k W2[e,k] pb[n,k]  (64x64 tiles, 2-slot drain).
//   Independent of the f8 path (W2,pb from prep) -> rides in the same launch
//   instead of serializing as its own 512-block kernel.
__global__ __launch_bounds__(256, 3)
void e_and_v2t(const unsigned char* __restrict__ Xq,   // [8192][512] fp8 e4m3
               const unsigned char* __restrict__ Pq,   // [4096][512] fp8 e4m3
               const unsigned short* __restrict__ W2,  // [512][512] bf16
               const unsigned short* __restrict__ pb,  // [4096][512] bf16
               unsigned short* __restrict__ Eg,        // [8192][4096] bf16
               unsigned short* __restrict__ v2T,       // [512][4096] bf16
               const float* __restrict__ x2g,
               const float* __restrict__ p2g,
               const float* __restrict__ scg,
               float* __restrict__ denom)
{
  __shared__ unsigned char smem[49152];       // f8: 3x16KB slots; v2T: 32KB

  const int tid  = threadIdx.x;
  const int lane = tid & 63;
  const int wv   = tid >> 6;
  const int l16  = lane & 15;
  const int quad = lane >> 4;
  const int lin  = blockIdx.x;

  if (lin < 2048) {
    // ================= f8 E path (R7 verbatim) =================
    constexpr int K = 512, N = 4096;
    constexpr int SLOT = 16384;
    const int wm = (wv >> 1) * 64;
    const int wn = (wv & 1) * 64;

    const int xcd = lin & 7, per = lin >> 3;
    const int xt = xcd * 4 + (per & 3), yt = per >> 2;
    const int n0 = xt * 128, m0 = yt * 128;

    f32x4 acc[4][4];
#pragma unroll
    for (int i = 0; i < 4; ++i)
#pragma unroll
      for (int j = 0; j < 4; ++j) {
        f32x4 z = {0.f, 0.f, 0.f, 0.f};
        acc[i][j] = z;
      }

    const unsigned char* gA[2]; const unsigned char* gB[2]; int lA[2];
#pragma unroll
    for (int i = 0; i < 2; ++i) {
      const int c = tid + i * 256;
      const int row = c >> 2;
      const int colb = ((c & 3) ^ ((row >> 2) & 3)) * 16;
      gA[i] = Xq + (size_t)(m0 + row) * K + colb;
      gB[i] = Pq + (size_t)(n0 + row) * K + colb;
      lA[i] = c * 16;
    }

    auto issue = [&](int sl, int kc) {
      unsigned char* S = smem + sl * SLOT;
#pragma unroll
      for (int i = 0; i < 2; ++i) gl_lds16(gA[i] + kc, &S[lA[i]]);
#pragma unroll
      for (int i = 0; i < 2; ++i) gl_lds16(gB[i] + kc, &S[8192 + lA[i]]);
    };

    auto compute = [&](int sl) {
      const unsigned char* As = smem + sl * SLOT;
      const unsigned char* Bs = As + 8192;
      __builtin_amdgcn_s_setprio(1);
#pragma unroll
      for (int sub = 0; sub < 2; ++sub) {
        long af[4], bq[4];
#pragma unroll
        for (int mi = 0; mi < 4; ++mi) {
          const int r = wm + mi * 16 + l16;
          af[mi] = *(const long*)&As[r * 64 +
                     (((sub * 2 + (quad >> 1)) ^ ((r >> 2) & 3)) * 16) + (quad & 1) * 8];
        }
#pragma unroll
        for (int ni = 0; ni < 4; ++ni) {
          const int r = wn + ni * 16 + l16;
          bq[ni] = *(const long*)&Bs[r * 64 +
                     (((sub * 2 + (quad >> 1)) ^ ((r >> 2) & 3)) * 16) + (quad & 1) * 8];
        }
#pragma unroll
        for (int mi = 0; mi < 4; ++mi)
#pragma unroll
          for (int ni = 0; ni < 4; ++ni)
            acc[mi][ni] = MFMA8(af[mi], bq[ni], acc[mi][ni], 0, 0, 0);
      }
      __builtin_amdgcn_s_setprio(0);
    };

    issue(0, 0);
    issue(1, 64);
    __builtin_amdgcn_s_waitcnt(0x0F74);
    __builtin_amdgcn_s_barrier();

    int s0 = 0, s1 = 1, s2 = 2;
#pragma unroll 1
    for (int it = 0; it < 8; ++it) {          // BK=64, nk=8
      if (it + 2 < 8) issue(s2, (it + 2) * 64);
      compute(s0);
      if (it + 2 < 8) __builtin_amdgcn_s_waitcnt(0x0F74);
      else            __builtin_amdgcn_s_waitcnt(0x0F70);
      __builtin_amdgcn_s_barrier();
      const int t = s0; s0 = s1; s1 = s2; s2 = t;
    }

    // epilogue: exp into 136-stride LDS tile, row sums, coalesced stores
    float p2v[4], scv[4];
#pragma unroll
    for (int ni = 0; ni < 4; ++ni) {
      const int n = n0 + wn + ni * 16 + l16;
      p2v[ni] = p2g[n];
      scv[ni] = scg[n] * 1.44269504088896f;   // fold log2(e)
    }
    __syncthreads();
    unsigned short* Es = (unsigned short*)smem;
#pragma unroll
    for (int mi = 0; mi < 4; ++mi) {
#pragma unroll
      for (int r = 0; r < 4; ++r) {
        const int rowL = wm + mi * 16 + quad * 4 + r;
        const float rowa = x2g[m0 + rowL];
        float s = 0.f;
#pragma unroll
        for (int ni = 0; ni < 4; ++ni) {
          const int col = wn + ni * 16 + l16;
          const float v = acc[mi][ni][r];
          float sq   = fmaxf(rowa - 2.0f * v + p2v[ni], 0.0f);
          float dist = __builtin_amdgcn_sqrtf(sq);
          float e    = __builtin_amdgcn_exp2f(scv[ni] * __builtin_amdgcn_rcpf(dist + 0.1f));
          Es[rowL * 136 + col] = f2bf(e);
          s += e;                             // unrounded sum (rel err ~3e-5)
        }
        s += __shfl_down(s, 8);
        s += __shfl_down(s, 4);
        s += __shfl_down(s, 2);
        s += __shfl_down(s, 1);
        if (l16 == 0) unsafeAtomicAdd(&denom[m0 + rowL], s);
      }
    }
    __syncthreads();
#pragma unroll
    for (int j = 0; j < 8; ++j) {
      const int cid = j * 256 + tid;
      const int row = cid >> 4, cc = cid & 15;
      bf16x8 v = *(const bf16x8*)&Es[row * 136 + cc * 8];
      *(bf16x8*)&Eg[(size_t)(m0 + row) * N + n0 + cc * 8] = v;
    }
  } else {
    // ================= v2T path: 64x64 tile, K=512 =================
    constexpr int ASZ = 64 * 64;              // shorts per slot (8 KB)
    unsigned short* As = (unsigned short*)smem;
    unsigned short* Bs = As + 2 * ASZ;

    const int idx = lin - 2048;               // [0,512)
    const int n0 = (idx & 63) * 64;
    const int m0 = (idx >> 6) * 64;

    f32x4 acc[4];
#pragma unroll
    for (int i = 0; i < 4; ++i) {
      f32x4 z = {0.f, 0.f, 0.f, 0.f};
      acc[i] = z;
    }

    const unsigned short* gA[2]; const unsigned short* gB[2]; int lc[2];
#pragma unroll
    for (int i = 0; i < 2; ++i) {
      const int c = tid + i * 256;
      const int row = c >> 3, col = ((c & 7) ^ (row & 7)) * 8;
      gA[i] = W2 + (size_t)(m0 + row) * 512 + col;
      gB[i] = pb + (size_t)(n0 + row) * 512 + col;
      lc[i] = c * 8;
    }

    auto issue = [&](int st, int kc) {
#pragma unroll
      for (int i = 0; i < 2; ++i) gl_lds16(gA[i] + kc, &As[st * ASZ + lc[i]]);
#pragma unroll
      for (int i = 0; i < 2; ++i) gl_lds16(gB[i] + kc, &Bs[st * ASZ + lc[i]]);
    };

    issue(0, 0);
    int cur = 0;
#pragma unroll 1
    for (int it = 0; it < 8; ++it) {          // BK=64, nk=8
      __builtin_amdgcn_s_barrier();
      if (it < 7) {
        issue(cur ^ 1, (it + 1) << 6);
        __builtin_amdgcn_s_waitcnt(0x0F74);
      } else {
        __builtin_amdgcn_s_waitcnt(0x0F70);
      }
      __builtin_amdgcn_s_barrier();

#pragma unroll
      for (int ks = 0; ks < 2; ++ks) {
        bf16x8 af[4], bfr;
#pragma unroll
        for (int mi = 0; mi < 4; ++mi) {
          const int r = mi * 16 + l16;
          af[mi] = *(const bf16x8*)&As[cur * ASZ + r * 64 + (((ks * 4 + quad) ^ (r & 7)) * 8)];
        }
        {
          const int r = wv * 16 + l16;
          bfr = *(const bf16x8*)&Bs[cur * ASZ + r * 64 + (((ks * 4 + quad) ^ (r & 7)) * 8)];
        }
#pragma unroll
        for (int mi = 0; mi < 4; ++mi)
          acc[mi] = MFMA(af[mi], bfr, acc[mi], 0, 0, 0);
      }
      cur ^= 1;
    }

#pragma unroll
    for (int mi = 0; mi < 4; ++mi) {
#pragma unroll
      for (int r = 0; r < 4; ++r) {
        const int m = m0 + mi * 16 + quad * 4 + r;
        const int n = n0 + wv * 16 + l16;
        v2T[(size_t)m * 4096 + n] = f2bf(acc[mi][r]);
      }
    }
  }
}

// ============ PV kernel (R7 verbatim): part[z][m,e] = sum_n E[m,n] v2T[e,n]
// BM=128, BN(e)=64, BK=64 fat steps, 48KB LDS -> 3 blocks/CU, nk=32.
// Grid 1024 (64m x 8e x 2z), m-octet pinned per XCD.
__global__ __launch_bounds__(256, 3)
void gemm_pv(const unsigned short* __restrict__ A,   // E: [8192][4096] bf16
             const unsigned short* __restrict__ B,   // v2T: [512][4096] bf16
             unsigned short* __restrict__ part)      // [2][8192][512] bf16
{
  constexpr int NCOL = 4096, KC = 2048;
  constexpr int ASZ = 128 * 64;   // shorts per A slot (16 KB)
  constexpr int BSZ = 64 * 64;    // shorts per B slot (8 KB)
  __shared__ unsigned short smem[2 * (ASZ + BSZ)];   // 48 KB
  unsigned short* As = smem;
  unsigned short* Bs = smem + 2 * ASZ;

  const int tid  = threadIdx.x;
  const int lane = tid & 63;
  const int wv   = tid >> 6;
  const int l16  = lane & 15;
  const int quad = lane >> 4;
  const int wm   = (wv >> 1) * 64;
  const int wn   = (wv & 1) * 32;

  const int lin = blockIdx.x;                 // 1024 blocks
  const int xcd = lin & 7, i = lin >> 3;
  const int yt  = xcd * 8 + (i & 7);
  const int combo = i >> 3;
  const int et  = combo & 7;
  const int zt  = combo >> 3;
  const int m0  = yt * 128;
  const int e0  = et * 64;
  const int kbeg = zt * KC;

  f32x4 acc[4][2];
#pragma unroll
  for (int a = 0; a < 4; ++a)
#pragma unroll
    for (int b = 0; b < 2; ++b) {
      f32x4 z = {0.f, 0.f, 0.f, 0.f};
      acc[a][b] = z;
    }

  const unsigned short* gA[4]; int lA[4];
  const unsigned short* gB[2]; int lB[2];
#pragma unroll
  for (int j = 0; j < 4; ++j) {
    const int c = tid + j * 256;
    const int row = c >> 3, col = ((c & 7) ^ (row & 7)) * 8;
    gA[j] = A + (size_t)(m0 + row) * NCOL + col + kbeg;
    lA[j] = c * 8;
  }
#pragma unroll
  for (int j = 0; j < 2; ++j) {
    const int c = tid + j * 256;
    const int row = c >> 3, col = ((c & 7) ^ (row & 7)) * 8;
    gB[j] = B + (size_t)(e0 + row) * NCOL + col + kbeg;
    lB[j] = c * 8;
  }

  auto issue = [&](int st, int kc) {
#pragma unroll
    for (int j = 0; j < 4; ++j) gl_lds16(gA[j] + kc, &As[st * ASZ + lA[j]]);
#pragma unroll
    for (int j = 0; j < 2; ++j) gl_lds16(gB[j] + kc, &Bs[st * BSZ + lB[j]]);
  };

  issue(0, 0);
  int cur = 0;
#pragma unroll 1
  for (int it = 0; it < 32; ++it) {           // BK=64, nk=32
    __builtin_amdgcn_s_barrier();
    if (it < 31) {
      issue(cur ^ 1, (it + 1) * 64);
      __builtin_amdgcn_s_waitcnt(0x0F76);
    } else {
      __builtin_amdgcn_s_waitcnt(0x0F70);
    }
    __builtin_amdgcn_s_barrier();

    __builtin_amdgcn_s_setprio(1);
#pragma unroll
    for (int ks = 0; ks < 2; ++ks) {
      bf16x8 af[4], bfr[2];
#pragma unroll
      for (int mi = 0; mi < 4; ++mi) {
        const int r = wm + mi * 16 + l16;
        af[mi] = *(const bf16x8*)&As[cur * ASZ + r * 64 + (((ks * 4 + quad) ^ (r & 7)) * 8)];
      }
#pragma unroll
      for (int ni = 0; ni < 2; ++ni) {
        const int r = wn + ni * 16 + l16;
        bfr[ni] = *(const bf16x8*)&Bs[cur * BSZ + r * 64 + (((ks * 4 + quad) ^ (r & 7)) * 8)];
      }
#pragma unroll
      for (int mi = 0; mi < 4; ++mi)
#pragma unroll
        for (int ni = 0; ni < 2; ++ni)
          acc[mi][ni] = MFMA(af[mi], bfr[ni], acc[mi][ni], 0, 0, 0);
    }
    __builtin_amdgcn_s_setprio(0);
    cur ^= 1;
  }

  unsigned short* Pz = part + (size_t)zt * (8192ull * 512);
#pragma unroll
  for (int mi = 0; mi < 4; ++mi) {
#pragma unroll
    for (int r = 0; r < 4; ++r) {
      const int m = m0 + wm + mi * 16 + quad * 4 + r;
#pragma unroll
      for (int ni = 0; ni < 2; ++ni) {
        const int e = e0 + wn + ni * 16 + l16;
        Pz[(size_t)m * 512 + e] = f2bf(acc[mi][ni][r]);
      }
    }
  }
}

// ===== prep_all: conversions/norms/bias + W2 GEMM in ONE launch (3264) =====
// [0,2048): x -> xq(fp8), x2, denom=0 ; [2048,3072): p -> pq(fp8), pb, p2 ;
// [3072,3200): bias2 = b_o + wo.b_v ; [3200,3264): W2 = wo.wv (64x64 tiles,
// direct f32 loads + in-reg cvt, no LDS/barriers: A-frags from contiguous wo
// rows, B-frags from coalesced wv column-slices).
__global__ void prep_all(const float* __restrict__ x, const float* __restrict__ positions,
                         const float* __restrict__ w_v, const float* __restrict__ w_o,
                         const float* __restrict__ b_v, const float* __restrict__ b_o,
                         unsigned char* __restrict__ xq, unsigned char* __restrict__ pq,
                         unsigned short* __restrict__ pb, unsigned short* __restrict__ W2,
                         float* __restrict__ x2, float* __restrict__ p2,
                         float* __restrict__ bias2, float* __restrict__ denom)
{
  const int b = blockIdx.x;
  const int tid = threadIdx.x;
  const int lane = tid & 63;
  const int wvz = tid >> 6;
  const int l16 = lane & 15;
  const int quad = lane >> 4;

  if (b < 3072) {
    const bool isx = (b < 2048);
    const int r = (isx ? b : b - 2048) * 4 + wvz;
    const float* X = isx ? x : positions;
    const float4* row = (const float4*)(X + (size_t)r * 512);
    const float4 a = row[lane];
    const float4 c = row[lane + 64];
    int wa = __builtin_amdgcn_cvt_pk_fp8_f32(a.x, a.y, 0, false);
    wa = __builtin_amdgcn_cvt_pk_fp8_f32(a.z, a.w, wa, true);
    int wc = __builtin_amdgcn_cvt_pk_fp8_f32(c.x, c.y, 0, false);
    wc = __builtin_amdgcn_cvt_pk_fp8_f32(c.z, c.w, wc, true);
    unsigned int* Q = (unsigned int*)(isx ? xq : pq) + (size_t)r * 128;
    Q[lane] = (unsigned int)wa;
    Q[lane + 64] = (unsigned int)wc;
    if (!isx) {                               // bf16 p kept for the v2T GEMM
      ushort4 ua, uc;
      ua.x = f2bf(a.x); ua.y = f2bf(a.y); ua.z = f2bf(a.z); ua.w = f2bf(a.w);
      uc.x = f2bf(c.x); uc.y = f2bf(c.y); uc.z = f2bf(c.z); uc.w = f2bf(c.w);
      ushort4* orow = (ushort4*)(pb + (size_t)r * 512);
      orow[lane] = ua;
      orow[lane + 64] = uc;
    }
    float s = a.x*a.x + a.y*a.y + a.z*a.z + a.w*a.w
            + c.x*c.x + c.y*c.y + c.z*c.z + c.w*c.w;
#pragma unroll
    for (int off = 32; off > 0; off >>= 1) s += __shfl_down(s, off, 64);
    if (lane == 0) {
      if (isx) { x2[r] = s; denom[r] = 0.f; }
      else     { p2[r] = s; }
    }
  } else if (b < 3200) {
    const int e = (b - 3072) * 4 + wvz;
    float s = 0.f;
#pragma unroll
    for (int j = 0; j < 8; ++j)
      s += w_o[(size_t)e * 512 + lane + j * 64] * b_v[lane + j * 64];
#pragma unroll
    for (int off = 32; off > 0; off >>= 1) s += __shfl_down(s, off, 64);
    if (lane == 0) bias2[e] = b_o[e] + s;   // softmax rows sum to 1
  } else {
    // W2[e,k] = sum_d wo[e,d] wv[d,k]; 64x64 tile per block
    const int idx = b - 3200;                 // [0,64)
    const int e0 = (idx >> 3) * 64;
    const int k0 = (idx & 7) * 64 + wvz * 16; // wave owns 16 k-cols

    f32x4 acc[4];
#pragma unroll
    for (int i = 0; i < 4; ++i) {
      f32x4 z = {0.f, 0.f, 0.f, 0.f};
      acc[i] = z;
    }

#pragma unroll 1
    for (int it = 0; it < 16; ++it) {         // K(d)=32 per step
      const int d0 = it * 32 + quad * 8;
      bf16x8 af[4], bq;
#pragma unroll
      for (int mi = 0; mi < 4; ++mi) {
        const float4 u = *(const float4*)&w_o[(size_t)(e0 + mi * 16 + l16) * 512 + d0];
        const float4 v = *(const float4*)&w_o[(size_t)(e0 + mi * 16 + l16) * 512 + d0 + 4];
        af[mi][0] = (short)f2bf(u.x); af[mi][1] = (short)f2bf(u.y);
        af[mi][2] = (short)f2bf(u.z); af[mi][3] = (short)f2bf(u.w);
        af[mi][4] = (short)f2bf(v.x); af[mi][5] = (short)f2bf(v.y);
        af[mi][6] = (short)f2bf(v.z); af[mi][7] = (short)f2bf(v.w);
      }
#pragma unroll
      for (int j = 0; j < 8; ++j)
        bq[j] = (short)f2bf(w_v[(size_t)(d0 + j) * 512 + k0 + l16]);
#pragma unroll
      for (int mi = 0; mi < 4; ++mi)
        acc[mi] = MFMA(af[mi], bq, acc[mi], 0, 0, 0);
    }

#pragma unroll
    for (int mi = 0; mi < 4; ++mi)
#pragma unroll
      for (int r = 0; r < 4; ++r)
        W2[(size_t)(e0 + mi * 16 + quad * 4 + r) * 512 + k0 + l16] = f2bf(acc[mi][r]);
  }
}

// out[m,e] = (P0[m,e] + P1[m,e]) / denom[m] + bias2[e]   (P bf16, out fp32)
__global__ void reduce_out(const unsigned short* __restrict__ P,
                           const float* __restrict__ denom,
                           const float* __restrict__ bias2,
                           float* __restrict__ out) {
  const int i = blockIdx.x * 256 + threadIdx.x;   // 1,048,576 float4s
  const int m = i >> 7;
  const float rd = 1.0f / denom[m];
  const float4 b4 = ((const float4*)bias2)[i & 127];
  const ushort4 p0 = ((const ushort4*)P)[i];
  const ushort4 p1 = ((const ushort4*)P)[i + 1048576];
  float4 o;
  o.x = (bf2f(p0.x) + bf2f(p1.x)) * rd + b4.x;
  o.y = (bf2f(p0.y) + bf2f(p1.y)) * rd + b4.y;
  o.z = (bf2f(p0.z) + bf2f(p1.z)) * rd + b4.z;
  o.w = (bf2f(p0.w) + bf2f(p1.w)) * rd + b4.w;
  ((float4*)out)[i] = o;
}

extern "C" void kernel_launch(void* const* d_in, const int* in_sizes, int n_in,
                              void* d_out, int out_size, void* d_ws, size_t ws_size,
                              hipStream_t stream) {
  const float* x         = (const float*)d_in[0];
  const float* positions = (const float*)d_in[1];
  const float* scale     = (const float*)d_in[2];
  const float* w_v       = (const float*)d_in[3];
  const float* b_v       = (const float*)d_in[4];
  const float* w_o       = (const float*)d_in[5];
  const float* b_o       = (const float*)d_in[6];
  float* out = (float*)d_out;

  char* base = (char*)d_ws;
  unsigned short* Eb    = (unsigned short*)(base + 0);          // 64 MB [E .. PV]
  unsigned short* v2T   = (unsigned short*)(base + 67108864);   // 4 MB
  float*          denom = (float*)(base + 71303168);            // 32 KB
  float*          x2    = (float*)(base + 71335936);            // 32 KB
  float*          p2    = (float*)(base + 71368704);            // 16 KB
  float*          bias2 = (float*)(base + 71385088);            // 2 KB
  char* base2 = base + 71387136;
  unsigned short* part  = (unsigned short*)base2;               // 16 MB [PV .. reduce]
  unsigned char*  xq    = (unsigned char*)base2;                // 4 MB  [prep .. E]
  unsigned char*  pq    = (unsigned char*)(base2 + 4194304);    // 2 MB  [prep .. E]
  unsigned short* pb    = (unsigned short*)(base2 + 6291456);   // 4 MB  [prep .. v2T]
  unsigned short* W2    = (unsigned short*)(base2 + 10485760);  // 0.5 MB [prep .. v2T]

  // prep: conversions/norms/bias + W2 = wo.wv   (3264 blocks)
  prep_all<<<3264, 256, 0, stream>>>(x, positions, w_v, w_o, b_v, b_o,
                                     xq, pq, pb, W2, x2, p2, bias2, denom);

  // merged: E[m,n]=exp(scale/(dist+0.1)) + denom  ||  v2T = W2 . pb^T
  e_and_v2t<<<2560, 256, 0, stream>>>(xq, pq, W2, pb, Eb, v2T,
                                      x2, p2, scale, denom);

  // part[z][m,e] = sum_{n in half z} E[m,n] v2T[e,n]
  gemm_pv<<<1024, 256, 0, stream>>>(Eb, v2T, part);

  // out = (part0 + part1)/denom + bias2
  reduce_out<<<4096, 256, 0, stream>>>(part, denom, bias2, out);
}

// Round 10
// 194.818 us; speedup vs baseline: 2.2680x; 1.1365x over previous
//
#include <hip/hip_runtime.h>
#include <cstdint>
#include <cstddef>

using bf16x8 = __attribute__((ext_vector_type(8))) short;
using f32x4  = __attribute__((ext_vector_type(4))) float;

__device__ __forceinline__ unsigned short f2bf(float f) {
  unsigned int u = __builtin_bit_cast(unsigned int, f);
  u += 0x7FFFu + ((u >> 16) & 1u);   // round-to-nearest-even
  return (unsigned short)(u >> 16);
}
__device__ __forceinline__ float bf2f(unsigned int h16) {
  unsigned int u = h16 << 16;
  return __builtin_bit_cast(float, u);
}

__device__ __forceinline__ void gl_lds16(const void* g, void* l) {
  __builtin_amdgcn_global_load_lds(
      (const __attribute__((address_space(1))) unsigned int*)g,
      (__attribute__((address_space(3))) unsigned int*)l,
      16, 0, 0);
}

#define MFMA  __builtin_amdgcn_mfma_f32_16x16x32_bf16
#define MFMA8 __builtin_amdgcn_mfma_f32_16x16x32_fp8_fp8

// ============ fp8 E-kernel (R6 variant — best measured: < 61.9us bound) ====
// 4 blocks/CU: BK=64 fp8 -> 8KB slots, 32KB staging, 34.8KB total with the
// epilogue transpose tile. 2-slot drain loop (3-slot dist-2 forces 3 blk/CU
// and measured WORSE: 67.5us in R7). 64-B rows, chunk-XOR s(r)=(r>>2)&3.
__global__ __launch_bounds__(256, 4)
void gemm_f8(const unsigned char* __restrict__ A,   // [8192][512] fp8 e4m3
             const unsigned char* __restrict__ B,   // [4096][512] fp8 e4m3
             unsigned short* __restrict__ Eg,       // [8192][4096] bf16
             const float* __restrict__ x2g,
             const float* __restrict__ p2g,
             const float* __restrict__ scg,
             float* __restrict__ denom)
{
  constexpr int K = 512, N = 4096;
  constexpr int ASZ = 128 * 64;               // bytes per slot (8 KB)
  __shared__ unsigned char smem[34816];       // staging 32 KB; epilogue 128x136x2
  unsigned char* As = smem;                   // A slots 0,1
  unsigned char* Bs = smem + 2 * ASZ;         // B slots 0,1

  const int tid  = threadIdx.x;
  const int lane = tid & 63;
  const int wv   = tid >> 6;
  const int wm   = (wv >> 1) * 64;
  const int wn   = (wv & 1) * 64;
  const int l16  = lane & 15;
  const int quad = lane >> 4;

  // 2048 blocks: XCD owns a 4-wide n-band (p-slice L2-resident per XCD)
  const int lin = blockIdx.x;
  const int xcd = lin & 7, per = lin >> 3;
  const int xt = xcd * 4 + (per & 3), yt = per >> 2;
  const int n0 = xt * 128, m0 = yt * 128;

  f32x4 acc[4][4];
#pragma unroll
  for (int i = 0; i < 4; ++i)
#pragma unroll
    for (int j = 0; j < 4; ++j) {
      f32x4 z = {0.f, 0.f, 0.f, 0.f};
      acc[i][j] = z;
    }

  // staging: c = tid + i*256 in [0,512): row=c>>2, slot chunk q=c&3,
  // global chunk = q ^ ((row>>2)&3)
  const unsigned char* gA[2]; const unsigned char* gB[2]; int lA[2];
#pragma unroll
  for (int i = 0; i < 2; ++i) {
    const int c = tid + i * 256;
    const int row = c >> 2;
    const int colb = ((c & 3) ^ ((row >> 2) & 3)) * 16;
    gA[i] = A + (size_t)(m0 + row) * K + colb;
    gB[i] = B + (size_t)(n0 + row) * K + colb;
    lA[i] = c * 16;
  }

  auto issue = [&](int st, int kc) {
#pragma unroll
    for (int i = 0; i < 2; ++i) gl_lds16(gA[i] + kc, &As[st * ASZ + lA[i]]);
#pragma unroll
    for (int i = 0; i < 2; ++i) gl_lds16(gB[i] + kc, &Bs[st * ASZ + lA[i]]);
  };

  issue(0, 0);
  int cur = 0;
#pragma unroll 1
  for (int it = 0; it < 8; ++it) {            // BK=64, nk=8
    __builtin_amdgcn_s_barrier();
    if (it < 7) {
      issue(cur ^ 1, (it + 1) * 64);
      __builtin_amdgcn_s_waitcnt(0x0F74);     // my 4 landed; next 4 in flight
    } else {
      __builtin_amdgcn_s_waitcnt(0x0F70);
    }
    __builtin_amdgcn_s_barrier();

#pragma unroll
    for (int sub = 0; sub < 2; ++sub) {       // 2 x K=32 sub-steps
      long af[4], bq[4];
#pragma unroll
      for (int mi = 0; mi < 4; ++mi) {
        const int r = wm + mi * 16 + l16;
        af[mi] = *(const long*)&As[cur * ASZ + r * 64 +
                   (((sub * 2 + (quad >> 1)) ^ ((r >> 2) & 3)) * 16) + (quad & 1) * 8];
      }
#pragma unroll
      for (int ni = 0; ni < 4; ++ni) {
        const int r = wn + ni * 16 + l16;
        bq[ni] = *(const long*)&Bs[cur * ASZ + r * 64 +
                   (((sub * 2 + (quad >> 1)) ^ ((r >> 2) & 3)) * 16) + (quad & 1) * 8];
      }
#pragma unroll
      for (int mi = 0; mi < 4; ++mi)
#pragma unroll
        for (int ni = 0; ni < 4; ++ni)
          acc[mi][ni] = MFMA8(af[mi], bq[ni], acc[mi][ni], 0, 0, 0);
    }
    cur ^= 1;
  }

  // ---- epilogue (proven): exp into 136-stride LDS tile, row sums, stores ----
  float p2v[4], scv[4];
#pragma unroll
  for (int ni = 0; ni < 4; ++ni) {
    const int n = n0 + wn + ni * 16 + l16;
    p2v[ni] = p2g[n];
    scv[ni] = scg[n] * 1.44269504088896f;     // fold log2(e)
  }
  __syncthreads();                            // done with K-loop LDS
  unsigned short* Es = (unsigned short*)smem; // 128 x (136-stride) bf16 tile
#pragma unroll
  for (int mi = 0; mi < 4; ++mi) {
#pragma unroll
    for (int r = 0; r < 4; ++r) {
      const int rowL = wm + mi * 16 + quad * 4 + r;
      const float rowa = x2g[m0 + rowL];
      float s = 0.f;
#pragma unroll
      for (int ni = 0; ni < 4; ++ni) {
        const int col = wn + ni * 16 + l16;
        const float v = acc[mi][ni][r];
        float sq   = fmaxf(rowa - 2.0f * v + p2v[ni], 0.0f);
        float dist = __builtin_amdgcn_sqrtf(sq);
        float e    = __builtin_amdgcn_exp2f(scv[ni] * __builtin_amdgcn_rcpf(dist + 0.1f));
        Es[rowL * 136 + col] = f2bf(e);
        s += e;                               // unrounded sum (rel err ~3e-5)
      }
      s += __shfl_down(s, 8);
      s += __shfl_down(s, 4);
      s += __shfl_down(s, 2);
      s += __shfl_down(s, 1);
      if (l16 == 0) unsafeAtomicAdd(&denom[m0 + rowL], s);
    }
  }
  __syncthreads();
#pragma unroll
  for (int j = 0; j < 8; ++j) {               // coalesced 16B stores
    const int cid = j * 256 + tid;
    const int row = cid >> 4, cc = cid & 15;
    bf16x8 v = *(const bf16x8*)&Es[row * 136 + cc * 8];
    *(bf16x8*)&Eg[(size_t)(m0 + row) * N + n0 + cc * 8] = v;
  }
}

// ============ PV kernel (R7 variant — part of the best measured total) =====
// part[z][m,e] = sum_{n in half z} E[m,n] v2T[e,n]
// BM=128, BN(e)=64, BK=64 fat steps, 48KB LDS -> 3 blocks/CU, nk=32,
// counted vmcnt(6). Grid 1024 (64m x 8e x 2z), m-octet pinned per XCD.
__global__ __launch_bounds__(256, 3)
void gemm_pv(const unsigned short* __restrict__ A,   // E: [8192][4096] bf16
             const unsigned short* __restrict__ B,   // v2T: [512][4096] bf16
             unsigned short* __restrict__ part)      // [2][8192][512] bf16
{
  constexpr int NCOL = 4096, KC = 2048;
  constexpr int ASZ = 128 * 64;   // shorts per A slot (16 KB)
  constexpr int BSZ = 64 * 64;    // shorts per B slot (8 KB)
  __shared__ unsigned short smem[2 * (ASZ + BSZ)];   // 48 KB
  unsigned short* As = smem;
  unsigned short* Bs = smem + 2 * ASZ;

  const int tid  = threadIdx.x;
  const int lane = tid & 63;
  const int wv   = tid >> 6;
  const int l16  = lane & 15;
  const int quad = lane >> 4;
  const int wm   = (wv >> 1) * 64;
  const int wn   = (wv & 1) * 32;

  const int lin = blockIdx.x;                 // 1024 blocks
  const int xcd = lin & 7, i = lin >> 3;
  const int yt  = xcd * 8 + (i & 7);
  const int combo = i >> 3;
  const int et  = combo & 7;
  const int zt  = combo >> 3;
  const int m0  = yt * 128;
  const int e0  = et * 64;
  const int kbeg = zt * KC;

  f32x4 acc[4][2];
#pragma unroll
  for (int a = 0; a < 4; ++a)
#pragma unroll
    for (int b = 0; b < 2; ++b) {
      f32x4 z = {0.f, 0.f, 0.f, 0.f};
      acc[a][b] = z;
    }

  const unsigned short* gA[4]; int lA[4];
  const unsigned short* gB[2]; int lB[2];
#pragma unroll
  for (int j = 0; j < 4; ++j) {
    const int c = tid + j * 256;
    const int row = c >> 3, col = ((c & 7) ^ (row & 7)) * 8;
    gA[j] = A + (size_t)(m0 + row) * NCOL + col + kbeg;
    lA[j] = c * 8;
  }
#pragma unroll
  for (int j = 0; j < 2; ++j) {
    const int c = tid + j * 256;
    const int row = c >> 3, col = ((c & 7) ^ (row & 7)) * 8;
    gB[j] = B + (size_t)(e0 + row) * NCOL + col + kbeg;
    lB[j] = c * 8;
  }

  auto issue = [&](int st, int kc) {
#pragma unroll
    for (int j = 0; j < 4; ++j) gl_lds16(gA[j] + kc, &As[st * ASZ + lA[j]]);
#pragma unroll
    for (int j = 0; j < 2; ++j) gl_lds16(gB[j] + kc, &Bs[st * BSZ + lB[j]]);
  };

  issue(0, 0);
  int cur = 0;
#pragma unroll 1
  for (int it = 0; it < 32; ++it) {           // BK=64, nk=32
    __builtin_amdgcn_s_barrier();
    if (it < 31) {
      issue(cur ^ 1, (it + 1) * 64);
      __builtin_amdgcn_s_waitcnt(0x0F76);     // my 6 landed; next 6 in flight
    } else {
      __builtin_amdgcn_s_waitcnt(0x0F70);
    }
    __builtin_amdgcn_s_barrier();

    __builtin_amdgcn_s_setprio(1);
#pragma unroll
    for (int ks = 0; ks < 2; ++ks) {
      bf16x8 af[4], bfr[2];
#pragma unroll
      for (int mi = 0; mi < 4; ++mi) {
        const int r = wm + mi * 16 + l16;
        af[mi] = *(const bf16x8*)&As[cur * ASZ + r * 64 + (((ks * 4 + quad) ^ (r & 7)) * 8)];
      }
#pragma unroll
      for (int ni = 0; ni < 2; ++ni) {
        const int r = wn + ni * 16 + l16;
        bfr[ni] = *(const bf16x8*)&Bs[cur * BSZ + r * 64 + (((ks * 4 + quad) ^ (r & 7)) * 8)];
      }
#pragma unroll
      for (int mi = 0; mi < 4; ++mi)
#pragma unroll
        for (int ni = 0; ni < 2; ++ni)
          acc[mi][ni] = MFMA(af[mi], bfr[ni], acc[mi][ni], 0, 0, 0);
    }
    __builtin_amdgcn_s_setprio(0);
    cur ^= 1;
  }

  unsigned short* Pz = part + (size_t)zt * (8192ull * 512);
#pragma unroll
  for (int mi = 0; mi < 4; ++mi) {
#pragma unroll
    for (int r = 0; r < 4; ++r) {
      const int m = m0 + wm + mi * 16 + quad * 4 + r;
#pragma unroll
      for (int ni = 0; ni < 2; ++ni) {
        const int e = e0 + wn + ni * 16 + l16;
        Pz[(size_t)m * 512 + e] = f2bf(acc[mi][ni][r]);
      }
    }
  }
}

// ============ 64x64-tile GEMM for the two small 512-K GEMMs ================
__global__ __launch_bounds__(256, 4)
void gemm64(const unsigned short* __restrict__ A,
            const unsigned short* __restrict__ B,
            unsigned short* __restrict__ C,
            int M, int N, int K)
{
  constexpr int ASZ = 64 * 64;    // shorts per slot (8 KB)
  __shared__ unsigned short smem[4 * ASZ];    // A0 A1 B0 B1 = 32 KB
  unsigned short* As = smem;
  unsigned short* Bs = smem + 2 * ASZ;

  const int tid  = threadIdx.x;
  const int lane = tid & 63;
  const int wv   = tid >> 6;
  const int l16  = lane & 15;
  const int quad = lane >> 4;

  const int n0 = blockIdx.x * 64;
  const int m0 = blockIdx.y * 64;

  f32x4 acc[4];
#pragma unroll
  for (int i = 0; i < 4; ++i) {
    f32x4 z = {0.f, 0.f, 0.f, 0.f};
    acc[i] = z;
  }

  const unsigned short* gA[2]; const unsigned short* gB[2]; int lc[2];
#pragma unroll
  for (int i = 0; i < 2; ++i) {
    const int c = tid + i * 256;
    const int row = c >> 3, col = ((c & 7) ^ (row & 7)) * 8;
    gA[i] = A + (size_t)(m0 + row) * K + col;
    gB[i] = B + (size_t)(n0 + row) * K + col;
    lc[i] = c * 8;
  }

  auto issue = [&](int st, int kc) {
#pragma unroll
    for (int i = 0; i < 2; ++i) gl_lds16(gA[i] + kc, &As[st * ASZ + lc[i]]);
#pragma unroll
    for (int i = 0; i < 2; ++i) gl_lds16(gB[i] + kc, &Bs[st * ASZ + lc[i]]);
  };

  const int nk = K >> 6;
  issue(0, 0);
  int cur = 0;
#pragma unroll 1
  for (int it = 0; it < nk; ++it) {
    __builtin_amdgcn_s_barrier();
    if (it + 1 < nk) {
      issue(cur ^ 1, (it + 1) << 6);
      __builtin_amdgcn_s_waitcnt(0x0F74);
    } else {
      __builtin_amdgcn_s_waitcnt(0x0F70);
    }
    __builtin_amdgcn_s_barrier();

#pragma unroll
    for (int ks = 0; ks < 2; ++ks) {
      bf16x8 af[4], bfr;
#pragma unroll
      for (int mi = 0; mi < 4; ++mi) {
        const int r = mi * 16 + l16;
        af[mi] = *(const bf16x8*)&As[cur * ASZ + r * 64 + (((ks * 4 + quad) ^ (r & 7)) * 8)];
      }
      {
        const int r = wv * 16 + l16;
        bfr = *(const bf16x8*)&Bs[cur * ASZ + r * 64 + (((ks * 4 + quad) ^ (r & 7)) * 8)];
      }
#pragma unroll
      for (int mi = 0; mi < 4; ++mi)
        acc[mi] = MFMA(af[mi], bfr, acc[mi], 0, 0, 0);
    }
    cur ^= 1;
  }

#pragma unroll
  for (int mi = 0; mi < 4; ++mi) {
#pragma unroll
    for (int r = 0; r < 4; ++r) {
      const int m = m0 + mi * 16 + quad * 4 + r;
      const int n = n0 + wv * 16 + l16;
      C[(size_t)m * N + n] = f2bf(acc[mi][r]);
    }
  }
}

// ===== prep_all: conversions/norms/bias in ONE launch (3456 blocks) =====
__global__ void prep_all(const float* __restrict__ x, const float* __restrict__ positions,
                         const float* __restrict__ w_v, const float* __restrict__ w_o,
                         const float* __restrict__ b_v, const float* __restrict__ b_o,
                         unsigned char* __restrict__ xq, unsigned char* __restrict__ pq,
                         unsigned short* __restrict__ pb,
                         unsigned short* __restrict__ wvb, unsigned short* __restrict__ wob,
                         float* __restrict__ x2, float* __restrict__ p2,
                         float* __restrict__ bias2, float* __restrict__ denom)
{
  const int b = blockIdx.x;
  const int tid = threadIdx.x;
  const int lane = tid & 63;
  const int wv = tid >> 6;

  if (b < 3072) {
    const bool isx = (b < 2048);
    const int r = (isx ? b : b - 2048) * 4 + wv;
    const float* X = isx ? x : positions;
    const float4* row = (const float4*)(X + (size_t)r * 512);
    const float4 a = row[lane];
    const float4 c = row[lane + 64];
    int wa = __builtin_amdgcn_cvt_pk_fp8_f32(a.x, a.y, 0, false);
    wa = __builtin_amdgcn_cvt_pk_fp8_f32(a.z, a.w, wa, true);
    int wc = __builtin_amdgcn_cvt_pk_fp8_f32(c.x, c.y, 0, false);
    wc = __builtin_amdgcn_cvt_pk_fp8_f32(c.z, c.w, wc, true);
    unsigned int* Q = (unsigned int*)(isx ? xq : pq) + (size_t)r * 128;
    Q[lane] = (unsigned int)wa;
    Q[lane + 64] = (unsigned int)wc;
    if (!isx) {                               // bf16 p kept for the val-GEMM
      ushort4 ua, uc;
      ua.x = f2bf(a.x); ua.y = f2bf(a.y); ua.z = f2bf(a.z); ua.w = f2bf(a.w);
      uc.x = f2bf(c.x); uc.y = f2bf(c.y); uc.z = f2bf(c.z); uc.w = f2bf(c.w);
      ushort4* orow = (ushort4*)(pb + (size_t)r * 512);
      orow[lane] = ua;
      orow[lane + 64] = uc;
    }
    float s = a.x*a.x + a.y*a.y + a.z*a.z + a.w*a.w
            + c.x*c.x + c.y*c.y + c.z*c.z + c.w*c.w;
#pragma unroll
    for (int off = 32; off > 0; off >>= 1) s += __shfl_down(s, off, 64);
    if (lane == 0) {
      if (isx) { x2[r] = s; denom[r] = 0.f; }
      else     { p2[r] = s; }
    }
  } else if (b < 3328) {
    const int i = (b - 3072) * 256 + tid;   // 65536 float4 each
    float4 a = ((const float4*)w_v)[i];
    float4 c = ((const float4*)w_o)[i];
    ushort4 ua, uc;
    ua.x = f2bf(a.x); ua.y = f2bf(a.y); ua.z = f2bf(a.z); ua.w = f2bf(a.w);
    uc.x = f2bf(c.x); uc.y = f2bf(c.y); uc.z = f2bf(c.z); uc.w = f2bf(c.w);
    ((ushort4*)wvb)[i] = ua;
    ((ushort4*)wob)[i] = uc;
  } else {
    const int e = (b - 3328) * 4 + wv;
    float s = 0.f;
#pragma unroll
    for (int j = 0; j < 8; ++j)
      s += w_o[(size_t)e * 512 + lane + j * 64] * b_v[lane + j * 64];
#pragma unroll
    for (int off = 32; off > 0; off >>= 1) s += __shfl_down(s, off, 64);
    if (lane == 0) bias2[e] = b_o[e] + s;   // softmax rows sum to 1
  }
}

// out[m,e] = (P0[m,e] + P1[m,e]) / denom[m] + bias2[e]   (P bf16, out fp32)
__global__ void reduce_out(const unsigned short* __restrict__ P,
                           const float* __restrict__ denom,
                           const float* __restrict__ bias2,
                           float* __restrict__ out) {
  const int i = blockIdx.x * 256 + threadIdx.x;   // 1,048,576 float4s
  const int m = i >> 7;
  const float rd = 1.0f / denom[m];
  const float4 b4 = ((const float4*)bias2)[i & 127];
  const ushort4 p0 = ((const ushort4*)P)[i];
  const ushort4 p1 = ((const ushort4*)P)[i + 1048576];
  float4 o;
  o.x = (bf2f(p0.x) + bf2f(p1.x)) * rd + b4.x;
  o.y = (bf2f(p0.y) + bf2f(p1.y)) * rd + b4.y;
  o.z = (bf2f(p0.z) + bf2f(p1.z)) * rd + b4.z;
  o.w = (bf2f(p0.w) + bf2f(p1.w)) * rd + b4.w;
  ((float4*)out)[i] = o;
}

extern "C" void kernel_launch(void* const* d_in, const int* in_sizes, int n_in,
                              void* d_out, int out_size, void* d_ws, size_t ws_size,
                              hipStream_t stream) {
  const float* x         = (const float*)d_in[0];
  const float* positions = (const float*)d_in[1];
  const float* scale     = (const float*)d_in[2];
  const float* w_v       = (const float*)d_in[3];
  const float* b_v       = (const float*)d_in[4];
  const float* w_o       = (const float*)d_in[5];
  const float* b_o       = (const float*)d_in[6];
  float* out = (float*)d_out;

  char* base = (char*)d_ws;
  unsigned short* Eb    = (unsigned short*)(base + 0);          // 64 MB [E .. PV]
  unsigned short* val   = (unsigned short*)(base + 0);          // 4 MB, parks in Eb
  unsigned short* v2T   = (unsigned short*)(base + 67108864);   // 4 MB
  float*          denom = (float*)(base + 71303168);            // 32 KB
  float*          x2    = (float*)(base + 71335936);            // 32 KB
  float*          p2    = (float*)(base + 71368704);            // 16 KB
  float*          bias2 = (float*)(base + 71385088);            // 2 KB
  char* base2 = base + 71387136;
  unsigned short* part  = (unsigned short*)base2;               // 16 MB [PV .. reduce]
  unsigned char*  xq    = (unsigned char*)base2;                // 4 MB  [prep .. E]
  unsigned char*  pq    = (unsigned char*)(base2 + 4194304);    // 2 MB  [prep .. E]
  unsigned short* pb    = (unsigned short*)(base2 + 6291456);   // 4 MB  [prep .. val]
  unsigned short* wvb   = (unsigned short*)(base2 + 10485760);  // 0.5 MB
  unsigned short* wo_b  = (unsigned short*)(base2 + 11010048);  // 0.5 MB

  // all prep in one launch
  prep_all<<<3456, 256, 0, stream>>>(x, positions, w_v, w_o, b_v, b_o,
                                     xq, pq, pb, wvb, wo_b, x2, p2, bias2, denom);

  // val[n,d] = sum_k p[n,k] wv[d,k]   (512 blocks of 64x64)
  gemm64<<<dim3(8, 64), 256, 0, stream>>>(pb, wvb, val, 4096, 512, 512);

  // v2T[e,n] = sum_d wo[e,d] val[n,d]   (512 blocks of 64x64)
  gemm64<<<dim3(64, 8), 256, 0, stream>>>(wo_b, val, v2T, 512, 4096, 512);

  // E[m,n] = exp(scale[n]/(dist+0.1)); denom[m] += row sums
  // fp8 BK=64, 34.8KB LDS -> 4 blocks/CU, 2-slot drain (R6 measured-best)
  gemm_f8<<<2048, 256, 0, stream>>>(xq, pq, Eb, x2, p2, scale, denom);

  // part[z][m,e] = sum_{n in half z} E[m,n] v2T[e,n]
  // 128x64x64 fat steps, 48KB -> 3 blocks/CU, counted vmcnt (R7)
  gemm_pv<<<1024, 256, 0, stream>>>(Eb, v2T, part);

  // out = (part0 + part1)/denom + bias2
  reduce_out<<<4096, 256, 0, stream>>>(part, denom, bias2, out);
}

// Round 11
// 190.100 us; speedup vs baseline: 2.3243x; 1.0248x over previous
//
#include <hip/hip_runtime.h>
#include <cstdint>
#include <cstddef>

using bf16x8 = __attribute__((ext_vector_type(8))) short;
using f32x4  = __attribute__((ext_vector_type(4))) float;

__device__ __forceinline__ unsigned short f2bf(float f) {
  unsigned int u = __builtin_bit_cast(unsigned int, f);
  u += 0x7FFFu + ((u >> 16) & 1u);   // round-to-nearest-even
  return (unsigned short)(u >> 16);
}
__device__ __forceinline__ float bf2f(unsigned int h16) {
  unsigned int u = h16 << 16;
  return __builtin_bit_cast(float, u);
}

__device__ __forceinline__ void gl_lds16(const void* g, void* l) {
  __builtin_amdgcn_global_load_lds(
      (const __attribute__((address_space(1))) unsigned int*)g,
      (__attribute__((address_space(3))) unsigned int*)l,
      16, 0, 0);
}

#define MFMA  __builtin_amdgcn_mfma_f32_16x16x32_bf16
#define MFMA8 __builtin_amdgcn_mfma_f32_16x16x32_fp8_fp8

// ============ merged launch 2: fp8 E-kernel (2048 blocks) + val GEMM (512) =
// Both depend only on prep outputs -> one launch kills one ~10us gap
// (R10 budget analysis: ~45us of the 194.8 total is inter-launch overhead).
// f8 path: R10-proven (56.2us): 4 blk/CU, BK=64, 2-slot counted-dist-1.
//   Epilogue tile stride 136 -> 140: quad row-stride 4*140 shorts = 280 dw
//   = {0,24,16,8} bank bases mod 32 -> disjoint 8-dword runs -> 2 lanes/bank
//   (was 4-way at 136: bases {0,16,0,16}). Kills the 4.46M write conflicts.
// val path: val[n,d] = sum_k pb[n,k] wvb[d,k] (64x64 tiles, R10 gemm64 body).
template<int DUMMY>
__global__ __launch_bounds__(256, 4)
void f8_and_val(const unsigned char* __restrict__ A,   // [8192][512] fp8 e4m3
                const unsigned char* __restrict__ B,   // [4096][512] fp8 e4m3
                unsigned short* __restrict__ Eg,       // [8192][4096] bf16
                const float* __restrict__ x2g,
                const float* __restrict__ p2g,
                const float* __restrict__ scg,
                float* __restrict__ denom,
                const unsigned short* __restrict__ pb,  // [4096][512] bf16
                const unsigned short* __restrict__ wvb, // [512][512] bf16
                unsigned short* __restrict__ val)       // [4096][512] bf16
{
  __shared__ unsigned char smem[35840];   // f8: 32KB staging / 128x140x2 epi
                                          // val: 32KB (4x8KB slots)
  const int tid  = threadIdx.x;
  const int lane = tid & 63;
  const int wv   = tid >> 6;
  const int l16  = lane & 15;
  const int quad = lane >> 4;
  const int lin  = blockIdx.x;

  if (lin < 2048) {
    // ================= f8 E path (R10 verbatim, epilogue stride 140) =======
    constexpr int K = 512, N = 4096;
    constexpr int ASZ = 128 * 64;             // bytes per slot (8 KB)
    unsigned char* As = smem;                 // A slots 0,1
    unsigned char* Bs = smem + 2 * ASZ;       // B slots 0,1
    const int wm = (wv >> 1) * 64;
    const int wn = (wv & 1) * 64;

    const int xcd = lin & 7, per = lin >> 3;
    const int xt = xcd * 4 + (per & 3), yt = per >> 2;
    const int n0 = xt * 128, m0 = yt * 128;

    f32x4 acc[4][4];
#pragma unroll
    for (int i = 0; i < 4; ++i)
#pragma unroll
      for (int j = 0; j < 4; ++j) {
        f32x4 z = {0.f, 0.f, 0.f, 0.f};
        acc[i][j] = z;
      }

    // staging: c = tid + i*256 in [0,512): row=c>>2, slot chunk q=c&3,
    // global chunk = q ^ ((row>>2)&3)
    const unsigned char* gA[2]; const unsigned char* gB[2]; int lA[2];
#pragma unroll
    for (int i = 0; i < 2; ++i) {
      const int c = tid + i * 256;
      const int row = c >> 2;
      const int colb = ((c & 3) ^ ((row >> 2) & 3)) * 16;
      gA[i] = A + (size_t)(m0 + row) * K + colb;
      gB[i] = B + (size_t)(n0 + row) * K + colb;
      lA[i] = c * 16;
    }

    auto issue = [&](int st, int kc) {
#pragma unroll
      for (int i = 0; i < 2; ++i) gl_lds16(gA[i] + kc, &As[st * ASZ + lA[i]]);
#pragma unroll
      for (int i = 0; i < 2; ++i) gl_lds16(gB[i] + kc, &Bs[st * ASZ + lA[i]]);
    };

    issue(0, 0);
    int cur = 0;
#pragma unroll 1
    for (int it = 0; it < 8; ++it) {          // BK=64, nk=8
      __builtin_amdgcn_s_barrier();
      if (it < 7) {
        issue(cur ^ 1, (it + 1) * 64);
        __builtin_amdgcn_s_waitcnt(0x0F74);   // my 4 landed; next 4 in flight
      } else {
        __builtin_amdgcn_s_waitcnt(0x0F70);
      }
      __builtin_amdgcn_s_barrier();

#pragma unroll
      for (int sub = 0; sub < 2; ++sub) {     // 2 x K=32 sub-steps
        long af[4], bq[4];
#pragma unroll
        for (int mi = 0; mi < 4; ++mi) {
          const int r = wm + mi * 16 + l16;
          af[mi] = *(const long*)&As[cur * ASZ + r * 64 +
                     (((sub * 2 + (quad >> 1)) ^ ((r >> 2) & 3)) * 16) + (quad & 1) * 8];
        }
#pragma unroll
        for (int ni = 0; ni < 4; ++ni) {
          const int r = wn + ni * 16 + l16;
          bq[ni] = *(const long*)&Bs[cur * ASZ + r * 64 +
                     (((sub * 2 + (quad >> 1)) ^ ((r >> 2) & 3)) * 16) + (quad & 1) * 8];
        }
#pragma unroll
        for (int mi = 0; mi < 4; ++mi)
#pragma unroll
          for (int ni = 0; ni < 4; ++ni)
            acc[mi][ni] = MFMA8(af[mi], bq[ni], acc[mi][ni], 0, 0, 0);
      }
      cur ^= 1;
    }

    // ---- epilogue: exp into 140-stride LDS tile, row sums, stores ----
    float p2v[4], scv[4];
#pragma unroll
    for (int ni = 0; ni < 4; ++ni) {
      const int n = n0 + wn + ni * 16 + l16;
      p2v[ni] = p2g[n];
      scv[ni] = scg[n] * 1.44269504088896f;   // fold log2(e)
    }
    __syncthreads();                          // done with K-loop LDS
    unsigned short* Es = (unsigned short*)smem;   // 128 x (140-stride) bf16
#pragma unroll
    for (int mi = 0; mi < 4; ++mi) {
#pragma unroll
      for (int r = 0; r < 4; ++r) {
        const int rowL = wm + mi * 16 + quad * 4 + r;
        const float rowa = x2g[m0 + rowL];
        float s = 0.f;
#pragma unroll
        for (int ni = 0; ni < 4; ++ni) {
          const int col = wn + ni * 16 + l16;
          const float v = acc[mi][ni][r];
          float sq   = fmaxf(rowa - 2.0f * v + p2v[ni], 0.0f);
          float dist = __builtin_amdgcn_sqrtf(sq);
          float e    = __builtin_amdgcn_exp2f(scv[ni] * __builtin_amdgcn_rcpf(dist + 0.1f));
          Es[rowL * 140 + col] = f2bf(e);
          s += e;                             // unrounded sum (rel err ~3e-5)
        }
        s += __shfl_down(s, 8);
        s += __shfl_down(s, 4);
        s += __shfl_down(s, 2);
        s += __shfl_down(s, 1);
        if (l16 == 0) unsafeAtomicAdd(&denom[m0 + rowL], s);
      }
    }
    __syncthreads();
#pragma unroll
    for (int j = 0; j < 8; ++j) {             // coalesced 16B stores
      const int cid = j * 256 + tid;
      const int row = cid >> 4, cc = cid & 15;
      bf16x8 v = *(const bf16x8*)&Es[row * 140 + cc * 8];
      *(bf16x8*)&Eg[(size_t)(m0 + row) * N + n0 + cc * 8] = v;
    }
  } else {
    // ================= val path: 64x64 tile, K=512 (gemm64 body) ===========
    constexpr int ASZ = 64 * 64;              // shorts per slot (8 KB)
    unsigned short* As = (unsigned short*)smem;
    unsigned short* Bs = As + 2 * ASZ;

    const int idx = lin - 2048;               // [0,512)
    const int n0 = (idx & 7) * 64;            // d-tile (512/64)
    const int m0 = (idx >> 3) * 64;           // n-tile (4096/64)

    f32x4 acc[4];
#pragma unroll
    for (int i = 0; i < 4; ++i) {
      f32x4 z = {0.f, 0.f, 0.f, 0.f};
      acc[i] = z;
    }

    const unsigned short* gA[2]; const unsigned short* gB[2]; int lc[2];
#pragma unroll
    for (int i = 0; i < 2; ++i) {
      const int c = tid + i * 256;
      const int row = c >> 3, col = ((c & 7) ^ (row & 7)) * 8;
      gA[i] = pb + (size_t)(m0 + row) * 512 + col;
      gB[i] = wvb + (size_t)(n0 + row) * 512 + col;
      lc[i] = c * 8;
    }

    auto issue = [&](int st, int kc) {
#pragma unroll
      for (int i = 0; i < 2; ++i) gl_lds16(gA[i] + kc, &As[st * ASZ + lc[i]]);
#pragma unroll
      for (int i = 0; i < 2; ++i) gl_lds16(gB[i] + kc, &Bs[st * ASZ + lc[i]]);
    };

    issue(0, 0);
    int cur = 0;
#pragma unroll 1
    for (int it = 0; it < 8; ++it) {          // BK=64, nk=8
      __builtin_amdgcn_s_barrier();
      if (it < 7) {
        issue(cur ^ 1, (it + 1) << 6);
        __builtin_amdgcn_s_waitcnt(0x0F74);
      } else {
        __builtin_amdgcn_s_waitcnt(0x0F70);
      }
      __builtin_amdgcn_s_barrier();

#pragma unroll
      for (int ks = 0; ks < 2; ++ks) {
        bf16x8 af[4], bfr;
#pragma unroll
        for (int mi = 0; mi < 4; ++mi) {
          const int r = mi * 16 + l16;
          af[mi] = *(const bf16x8*)&As[cur * ASZ + r * 64 + (((ks * 4 + quad) ^ (r & 7)) * 8)];
        }
        {
          const int r = wv * 16 + l16;
          bfr = *(const bf16x8*)&Bs[cur * ASZ + r * 64 + (((ks * 4 + quad) ^ (r & 7)) * 8)];
        }
#pragma unroll
        for (int mi = 0; mi < 4; ++mi)
          acc[mi] = MFMA(af[mi], bfr, acc[mi], 0, 0, 0);
      }
      cur ^= 1;
    }

#pragma unroll
    for (int mi = 0; mi < 4; ++mi) {
#pragma unroll
      for (int r = 0; r < 4; ++r) {
        const int m = m0 + mi * 16 + quad * 4 + r;
        const int n = n0 + wv * 16 + l16;
        val[(size_t)m * 512 + n] = f2bf(acc[mi][r]);
      }
    }
  }
}

// ============ PV kernel (R7/R10 verbatim) ==================================
// part[z][m,e] = sum_{n in half z} E[m,n] v2T[e,n]
// BM=128, BN(e)=64, BK=64 fat steps, 48KB LDS -> 3 blocks/CU, nk=32,
// counted vmcnt(6). Grid 1024 (64m x 8e x 2z), m-octet pinned per XCD.
__global__ __launch_bounds__(256, 3)
void gemm_pv(const unsigned short* __restrict__ A,   // E: [8192][4096] bf16
             const unsigned short* __restrict__ B,   // v2T: [512][4096] bf16
             unsigned short* __restrict__ part)      // [2][8192][512] bf16
{
  constexpr int NCOL = 4096, KC = 2048;
  constexpr int ASZ = 128 * 64;   // shorts per A slot (16 KB)
  constexpr int BSZ = 64 * 64;    // shorts per B slot (8 KB)
  __shared__ unsigned short smem[2 * (ASZ + BSZ)];   // 48 KB
  unsigned short* As = smem;
  unsigned short* Bs = smem + 2 * ASZ;

  const int tid  = threadIdx.x;
  const int lane = tid & 63;
  const int wv   = tid >> 6;
  const int l16  = lane & 15;
  const int quad = lane >> 4;
  const int wm   = (wv >> 1) * 64;
  const int wn   = (wv & 1) * 32;

  const int lin = blockIdx.x;                 // 1024 blocks
  const int xcd = lin & 7, i = lin >> 3;
  const int yt  = xcd * 8 + (i & 7);
  const int combo = i >> 3;
  const int et  = combo & 7;
  const int zt  = combo >> 3;
  const int m0  = yt * 128;
  const int e0  = et * 64;
  const int kbeg = zt * KC;

  f32x4 acc[4][2];
#pragma unroll
  for (int a = 0; a < 4; ++a)
#pragma unroll
    for (int b = 0; b < 2; ++b) {
      f32x4 z = {0.f, 0.f, 0.f, 0.f};
      acc[a][b] = z;
    }

  const unsigned short* gA[4]; int lA[4];
  const unsigned short* gB[2]; int lB[2];
#pragma unroll
  for (int j = 0; j < 4; ++j) {
    const int c = tid + j * 256;
    const int row = c >> 3, col = ((c & 7) ^ (row & 7)) * 8;
    gA[j] = A + (size_t)(m0 + row) * NCOL + col + kbeg;
    lA[j] = c * 8;
  }
#pragma unroll
  for (int j = 0; j < 2; ++j) {
    const int c = tid + j * 256;
    const int row = c >> 3, col = ((c & 7) ^ (row & 7)) * 8;
    gB[j] = B + (size_t)(e0 + row) * NCOL + col + kbeg;
    lB[j] = c * 8;
  }

  auto issue = [&](int st, int kc) {
#pragma unroll
    for (int j = 0; j < 4; ++j) gl_lds16(gA[j] + kc, &As[st * ASZ + lA[j]]);
#pragma unroll
    for (int j = 0; j < 2; ++j) gl_lds16(gB[j] + kc, &Bs[st * BSZ + lB[j]]);
  };

  issue(0, 0);
  int cur = 0;
#pragma unroll 1
  for (int it = 0; it < 32; ++it) {           // BK=64, nk=32
    __builtin_amdgcn_s_barrier();
    if (it < 31) {
      issue(cur ^ 1, (it + 1) * 64);
      __builtin_amdgcn_s_waitcnt(0x0F76);     // my 6 landed; next 6 in flight
    } else {
      __builtin_amdgcn_s_waitcnt(0x0F70);
    }
    __builtin_amdgcn_s_barrier();

    __builtin_amdgcn_s_setprio(1);
#pragma unroll
    for (int ks = 0; ks < 2; ++ks) {
      bf16x8 af[4], bfr[2];
#pragma unroll
      for (int mi = 0; mi < 4; ++mi) {
        const int r = wm + mi * 16 + l16;
        af[mi] = *(const bf16x8*)&As[cur * ASZ + r * 64 + (((ks * 4 + quad) ^ (r & 7)) * 8)];
      }
#pragma unroll
      for (int ni = 0; ni < 2; ++ni) {
        const int r = wn + ni * 16 + l16;
        bfr[ni] = *(const bf16x8*)&Bs[cur * BSZ + r * 64 + (((ks * 4 + quad) ^ (r & 7)) * 8)];
      }
#pragma unroll
      for (int mi = 0; mi < 4; ++mi)
#pragma unroll
        for (int ni = 0; ni < 2; ++ni)
          acc[mi][ni] = MFMA(af[mi], bfr[ni], acc[mi][ni], 0, 0, 0);
    }
    __builtin_amdgcn_s_setprio(0);
    cur ^= 1;
  }

  unsigned short* Pz = part + (size_t)zt * (8192ull * 512);
#pragma unroll
  for (int mi = 0; mi < 4; ++mi) {
#pragma unroll
    for (int r = 0; r < 4; ++r) {
      const int m = m0 + wm + mi * 16 + quad * 4 + r;
#pragma unroll
      for (int ni = 0; ni < 2; ++ni) {
        const int e = e0 + wn + ni * 16 + l16;
        Pz[(size_t)m * 512 + e] = f2bf(acc[mi][ni][r]);
      }
    }
  }
}

// ============ 64x64-tile GEMM (v2T launch) =================================
__global__ __launch_bounds__(256, 4)
void gemm64(const unsigned short* __restrict__ A,
            const unsigned short* __restrict__ B,
            unsigned short* __restrict__ C,
            int M, int N, int K)
{
  constexpr int ASZ = 64 * 64;    // shorts per slot (8 KB)
  __shared__ unsigned short smem[4 * ASZ];    // A0 A1 B0 B1 = 32 KB
  unsigned short* As = smem;
  unsigned short* Bs = smem + 2 * ASZ;

  const int tid  = threadIdx.x;
  const int lane = tid & 63;
  const int wv   = tid >> 6;
  const int l16  = lane & 15;
  const int quad = lane >> 4;

  const int n0 = blockIdx.x * 64;
  const int m0 = blockIdx.y * 64;

  f32x4 acc[4];
#pragma unroll
  for (int i = 0; i < 4; ++i) {
    f32x4 z = {0.f, 0.f, 0.f, 0.f};
    acc[i] = z;
  }

  const unsigned short* gA[2]; const unsigned short* gB[2]; int lc[2];
#pragma unroll
  for (int i = 0; i < 2; ++i) {
    const int c = tid + i * 256;
    const int row = c >> 3, col = ((c & 7) ^ (row & 7)) * 8;
    gA[i] = A + (size_t)(m0 + row) * K + col;
    gB[i] = B + (size_t)(n0 + row) * K + col;
    lc[i] = c * 8;
  }

  auto issue = [&](int st, int kc) {
#pragma unroll
    for (int i = 0; i < 2; ++i) gl_lds16(gA[i] + kc, &As[st * ASZ + lc[i]]);
#pragma unroll
    for (int i = 0; i < 2; ++i) gl_lds16(gB[i] + kc, &Bs[st * ASZ + lc[i]]);
  };

  const int nk = K >> 6;
  issue(0, 0);
  int cur = 0;
#pragma unroll 1
  for (int it = 0; it < nk; ++it) {
    __builtin_amdgcn_s_barrier();
    if (it + 1 < nk) {
      issue(cur ^ 1, (it + 1) << 6);
      __builtin_amdgcn_s_waitcnt(0x0F74);
    } else {
      __builtin_amdgcn_s_waitcnt(0x0F70);
    }
    __builtin_amdgcn_s_barrier();

#pragma unroll
    for (int ks = 0; ks < 2; ++ks) {
      bf16x8 af[4], bfr;
#pragma unroll
      for (int mi = 0; mi < 4; ++mi) {
        const int r = mi * 16 + l16;
        af[mi] = *(const bf16x8*)&As[cur * ASZ + r * 64 + (((ks * 4 + quad) ^ (r & 7)) * 8)];
      }
      {
        const int r = wv * 16 + l16;
        bfr = *(const bf16x8*)&Bs[cur * ASZ + r * 64 + (((ks * 4 + quad) ^ (r & 7)) * 8)];
      }
#pragma unroll
      for (int mi = 0; mi < 4; ++mi)
        acc[mi] = MFMA(af[mi], bfr, acc[mi], 0, 0, 0);
    }
    cur ^= 1;
  }

#pragma unroll
  for (int mi = 0; mi < 4; ++mi) {
#pragma unroll
    for (int r = 0; r < 4; ++r) {
      const int m = m0 + mi * 16 + quad * 4 + r;
      const int n = n0 + wv * 16 + l16;
      C[(size_t)m * N + n] = f2bf(acc[mi][r]);
    }
  }
}

// ===== prep_all: conversions/norms/bias in ONE launch (3456 blocks) =====
__global__ void prep_all(const float* __restrict__ x, const float* __restrict__ positions,
                         const float* __restrict__ w_v, const float* __restrict__ w_o,
                         const float* __restrict__ b_v, const float* __restrict__ b_o,
                         unsigned char* __restrict__ xq, unsigned char* __restrict__ pq,
                         unsigned short* __restrict__ pb,
                         unsigned short* __restrict__ wvb, unsigned short* __restrict__ wob,
                         float* __restrict__ x2, float* __restrict__ p2,
                         float* __restrict__ bias2, float* __restrict__ denom)
{
  const int b = blockIdx.x;
  const int tid = threadIdx.x;
  const int lane = tid & 63;
  const int wv = tid >> 6;

  if (b < 3072) {
    const bool isx = (b < 2048);
    const int r = (isx ? b : b - 2048) * 4 + wv;
    const float* X = isx ? x : positions;
    const float4* row = (const float4*)(X + (size_t)r * 512);
    const float4 a = row[lane];
    const float4 c = row[lane + 64];
    int wa = __builtin_amdgcn_cvt_pk_fp8_f32(a.x, a.y, 0, false);
    wa = __builtin_amdgcn_cvt_pk_fp8_f32(a.z, a.w, wa, true);
    int wc = __builtin_amdgcn_cvt_pk_fp8_f32(c.x, c.y, 0, false);
    wc = __builtin_amdgcn_cvt_pk_fp8_f32(c.z, c.w, wc, true);
    unsigned int* Q = (unsigned int*)(isx ? xq : pq) + (size_t)r * 128;
    Q[lane] = (unsigned int)wa;
    Q[lane + 64] = (unsigned int)wc;
    if (!isx) {                               // bf16 p kept for the val-GEMM
      ushort4 ua, uc;
      ua.x = f2bf(a.x); ua.y = f2bf(a.y); ua.z = f2bf(a.z); ua.w = f2bf(a.w);
      uc.x = f2bf(c.x); uc.y = f2bf(c.y); uc.z = f2bf(c.z); uc.w = f2bf(c.w);
      ushort4* orow = (ushort4*)(pb + (size_t)r * 512);
      orow[lane] = ua;
      orow[lane + 64] = uc;
    }
    float s = a.x*a.x + a.y*a.y + a.z*a.z + a.w*a.w
            + c.x*c.x + c.y*c.y + c.z*c.z + c.w*c.w;
#pragma unroll
    for (int off = 32; off > 0; off >>= 1) s += __shfl_down(s, off, 64);
    if (lane == 0) {
      if (isx) { x2[r] = s; denom[r] = 0.f; }
      else     { p2[r] = s; }
    }
  } else if (b < 3328) {
    const int i = (b - 3072) * 256 + tid;   // 65536 float4 each
    float4 a = ((const float4*)w_v)[i];
    float4 c = ((const float4*)w_o)[i];
    ushort4 ua, uc;
    ua.x = f2bf(a.x); ua.y = f2bf(a.y); ua.z = f2bf(a.z); ua.w = f2bf(a.w);
    uc.x = f2bf(c.x); uc.y = f2bf(c.y); uc.z = f2bf(c.z); uc.w = f2bf(c.w);
    ((ushort4*)wvb)[i] = ua;
    ((ushort4*)wob)[i] = uc;
  } else {
    const int e = (b - 3328) * 4 + wv;
    float s = 0.f;
#pragma unroll
    for (int j = 0; j < 8; ++j)
      s += w_o[(size_t)e * 512 + lane + j * 64] * b_v[lane + j * 64];
#pragma unroll
    for (int off = 32; off > 0; off >>= 1) s += __shfl_down(s, off, 64);
    if (lane == 0) bias2[e] = b_o[e] + s;   // softmax rows sum to 1
  }
}

// out[m,e] = (P0[m,e] + P1[m,e]) / denom[m] + bias2[e]   (P bf16, out fp32)
__global__ void reduce_out(const unsigned short* __restrict__ P,
                           const float* __restrict__ denom,
                           const float* __restrict__ bias2,
                           float* __restrict__ out) {
  const int i = blockIdx.x * 256 + threadIdx.x;   // 1,048,576 float4s
  const int m = i >> 7;
  const float rd = 1.0f / denom[m];
  const float4 b4 = ((const float4*)bias2)[i & 127];
  const ushort4 p0 = ((const ushort4*)P)[i];
  const ushort4 p1 = ((const ushort4*)P)[i + 1048576];
  float4 o;
  o.x = (bf2f(p0.x) + bf2f(p1.x)) * rd + b4.x;
  o.y = (bf2f(p0.y) + bf2f(p1.y)) * rd + b4.y;
  o.z = (bf2f(p0.z) + bf2f(p1.z)) * rd + b4.z;
  o.w = (bf2f(p0.w) + bf2f(p1.w)) * rd + b4.w;
  ((float4*)out)[i] = o;
}

extern "C" void kernel_launch(void* const* d_in, const int* in_sizes, int n_in,
                              void* d_out, int out_size, void* d_ws, size_t ws_size,
                              hipStream_t stream) {
  const float* x         = (const float*)d_in[0];
  const float* positions = (const float*)d_in[1];
  const float* scale     = (const float*)d_in[2];
  const float* w_v       = (const float*)d_in[3];
  const float* b_v       = (const float*)d_in[4];
  const float* w_o       = (const float*)d_in[5];
  const float* b_o       = (const float*)d_in[6];
  float* out = (float*)d_out;

  char* base = (char*)d_ws;
  unsigned short* Eb    = (unsigned short*)(base + 0);          // 64 MB [E .. PV]
  unsigned short* val   = (unsigned short*)(base + 0);          // 4 MB, parks in Eb
  unsigned short* v2T   = (unsigned short*)(base + 67108864);   // 4 MB
  float*          denom = (float*)(base + 71303168);            // 32 KB
  float*          x2    = (float*)(base + 71335936);            // 32 KB
  float*          p2    = (float*)(base + 71368704);            // 16 KB
  float*          bias2 = (float*)(base + 71385088);            // 2 KB
  char* base2 = base + 71387136;
  unsigned short* part  = (unsigned short*)base2;               // 16 MB [PV .. reduce]
  unsigned char*  xq    = (unsigned char*)base2;                // 4 MB  [prep .. E]
  unsigned char*  pq    = (unsigned char*)(base2 + 4194304);    // 2 MB  [prep .. E]
  unsigned short* pb    = (unsigned short*)(base2 + 6291456);   // 4 MB  [prep .. val]
  unsigned short* wvb   = (unsigned short*)(base2 + 10485760);  // 0.5 MB
  unsigned short* wo_b  = (unsigned short*)(base2 + 11010048);  // 0.5 MB

  // NOTE: val parks at Eb base (4 MB) -- the f8 path of the merged launch
  // writes E tiles starting at Eb too. Collision check: val occupies Eb rows
  // m<512 region... AVOID: park val AFTER v2T instead.
  unsigned short* val2  = (unsigned short*)(base2 + 11534336);  // 4 MB [merged .. v2T]

  // all prep in one launch
  prep_all<<<3456, 256, 0, stream>>>(x, positions, w_v, w_o, b_v, b_o,
                                     xq, pq, pb, wvb, wo_b, x2, p2, bias2, denom);

  // merged: E[m,n]=exp(scale/(dist+0.1)) + denom  ||  val = pb . wvb^T
  f8_and_val<0><<<2560, 256, 0, stream>>>(xq, pq, Eb, x2, p2, scale, denom,
                                          pb, wvb, val2);

  // v2T[e,n] = sum_d wo[e,d] val[n,d]   (512 blocks of 64x64)
  gemm64<<<dim3(64, 8), 256, 0, stream>>>(wo_b, val2, v2T, 512, 4096, 512);

  // part[z][m,e] = sum_{n in half z} E[m,n] v2T[e,n]
  gemm_pv<<<1024, 256, 0, stream>>>(Eb, v2T, part);

  // out = (part0 + part1)/denom + bias2
  reduce_out<<<4096, 256, 0, stream>>>(part, denom, bias2, out);
}

// Round 12
// 181.025 us; speedup vs baseline: 2.4408x; 1.0501x over previous
//
#include <hip/hip_runtime.h>
#include <cstdint>
#include <cstddef>

using bf16x8 = __attribute__((ext_vector_type(8))) short;
using f32x4  = __attribute__((ext_vector_type(4))) float;

__device__ __forceinline__ unsigned short f2bf(float f) {
  unsigned int u = __builtin_bit_cast(unsigned int, f);
  u += 0x7FFFu + ((u >> 16) & 1u);   // round-to-nearest-even
  return (unsigned short)(u >> 16);
}
__device__ __forceinline__ float bf2f(unsigned int h16) {
  unsigned int u = h16 << 16;
  return __builtin_bit_cast(float, u);
}

__device__ __forceinline__ void gl_lds16(const void* g, void* l) {
  __builtin_amdgcn_global_load_lds(
      (const __attribute__((address_space(1))) unsigned int*)g,
      (__attribute__((address_space(3))) unsigned int*)l,
      16, 0, 0);
}

#define MFMA  __builtin_amdgcn_mfma_f32_16x16x32_bf16
#define MFMA8 __builtin_amdgcn_mfma_f32_16x16x32_fp8_fp8

// ============ merged launch 2: fp8 E-kernel (2048 blocks) + val GEMM (512) =
// R11-proven (61.5us). f8: 4 blk/CU, BK=64, 2-slot counted-dist-1; epilogue
// stride-140 tile. val: 64x64 tiles (gemm64 body). Residual 4.19M bank
// "conflicts" are the fp8 ds_read_b64 at its 4-deep throughput minimum
// (128 dwords / 32 banks) -- not actual stalls; closed as unfixable.
template<int DUMMY>
__global__ __launch_bounds__(256, 4)
void f8_and_val(const unsigned char* __restrict__ A,   // [8192][512] fp8 e4m3
                const unsigned char* __restrict__ B,   // [4096][512] fp8 e4m3
                unsigned short* __restrict__ Eg,       // [8192][4096] bf16
                const float* __restrict__ x2g,
                const float* __restrict__ p2g,
                const float* __restrict__ scg,
                float* __restrict__ denom,
                const unsigned short* __restrict__ pb,  // [4096][512] bf16
                const unsigned short* __restrict__ wvb, // [512][512] bf16
                unsigned short* __restrict__ val)       // [4096][512] bf16
{
  __shared__ unsigned char smem[35840];   // f8: 32KB staging / 128x140x2 epi
                                          // val: 32KB (4x8KB slots)
  const int tid  = threadIdx.x;
  const int lane = tid & 63;
  const int wv   = tid >> 6;
  const int l16  = lane & 15;
  const int quad = lane >> 4;
  const int lin  = blockIdx.x;

  if (lin < 2048) {
    // ================= f8 E path =================
    constexpr int K = 512, N = 4096;
    constexpr int ASZ = 128 * 64;             // bytes per slot (8 KB)
    unsigned char* As = smem;                 // A slots 0,1
    unsigned char* Bs = smem + 2 * ASZ;       // B slots 0,1
    const int wm = (wv >> 1) * 64;
    const int wn = (wv & 1) * 64;

    const int xcd = lin & 7, per = lin >> 3;
    const int xt = xcd * 4 + (per & 3), yt = per >> 2;
    const int n0 = xt * 128, m0 = yt * 128;

    f32x4 acc[4][4];
#pragma unroll
    for (int i = 0; i < 4; ++i)
#pragma unroll
      for (int j = 0; j < 4; ++j) {
        f32x4 z = {0.f, 0.f, 0.f, 0.f};
        acc[i][j] = z;
      }

    const unsigned char* gA[2]; const unsigned char* gB[2]; int lA[2];
#pragma unroll
    for (int i = 0; i < 2; ++i) {
      const int c = tid + i * 256;
      const int row = c >> 2;
      const int colb = ((c & 3) ^ ((row >> 2) & 3)) * 16;
      gA[i] = A + (size_t)(m0 + row) * K + colb;
      gB[i] = B + (size_t)(n0 + row) * K + colb;
      lA[i] = c * 16;
    }

    auto issue = [&](int st, int kc) {
#pragma unroll
      for (int i = 0; i < 2; ++i) gl_lds16(gA[i] + kc, &As[st * ASZ + lA[i]]);
#pragma unroll
      for (int i = 0; i < 2; ++i) gl_lds16(gB[i] + kc, &Bs[st * ASZ + lA[i]]);
    };

    issue(0, 0);
    int cur = 0;
#pragma unroll 1
    for (int it = 0; it < 8; ++it) {          // BK=64, nk=8
      __builtin_amdgcn_s_barrier();
      if (it < 7) {
        issue(cur ^ 1, (it + 1) * 64);
        __builtin_amdgcn_s_waitcnt(0x0F74);   // my 4 landed; next 4 in flight
      } else {
        __builtin_amdgcn_s_waitcnt(0x0F70);
      }
      __builtin_amdgcn_s_barrier();

#pragma unroll
      for (int sub = 0; sub < 2; ++sub) {     // 2 x K=32 sub-steps
        long af[4], bq[4];
#pragma unroll
        for (int mi = 0; mi < 4; ++mi) {
          const int r = wm + mi * 16 + l16;
          af[mi] = *(const long*)&As[cur * ASZ + r * 64 +
                     (((sub * 2 + (quad >> 1)) ^ ((r >> 2) & 3)) * 16) + (quad & 1) * 8];
        }
#pragma unroll
        for (int ni = 0; ni < 4; ++ni) {
          const int r = wn + ni * 16 + l16;
          bq[ni] = *(const long*)&Bs[cur * ASZ + r * 64 +
                     (((sub * 2 + (quad >> 1)) ^ ((r >> 2) & 3)) * 16) + (quad & 1) * 8];
        }
#pragma unroll
        for (int mi = 0; mi < 4; ++mi)
#pragma unroll
          for (int ni = 0; ni < 4; ++ni)
            acc[mi][ni] = MFMA8(af[mi], bq[ni], acc[mi][ni], 0, 0, 0);
      }
      cur ^= 1;
    }

    // ---- epilogue: exp into 140-stride LDS tile, row sums, stores ----
    float p2v[4], scv[4];
#pragma unroll
    for (int ni = 0; ni < 4; ++ni) {
      const int n = n0 + wn + ni * 16 + l16;
      p2v[ni] = p2g[n];
      scv[ni] = scg[n] * 1.44269504088896f;   // fold log2(e)
    }
    __syncthreads();                          // done with K-loop LDS
    unsigned short* Es = (unsigned short*)smem;   // 128 x (140-stride) bf16
#pragma unroll
    for (int mi = 0; mi < 4; ++mi) {
#pragma unroll
      for (int r = 0; r < 4; ++r) {
        const int rowL = wm + mi * 16 + quad * 4 + r;
        const float rowa = x2g[m0 + rowL];
        float s = 0.f;
#pragma unroll
        for (int ni = 0; ni < 4; ++ni) {
          const int col = wn + ni * 16 + l16;
          const float v = acc[mi][ni][r];
          float sq   = fmaxf(rowa - 2.0f * v + p2v[ni], 0.0f);
          float dist = __builtin_amdgcn_sqrtf(sq);
          float e    = __builtin_amdgcn_exp2f(scv[ni] * __builtin_amdgcn_rcpf(dist + 0.1f));
          Es[rowL * 140 + col] = f2bf(e);
          s += e;                             // unrounded sum (rel err ~3e-5)
        }
        s += __shfl_down(s, 8);
        s += __shfl_down(s, 4);
        s += __shfl_down(s, 2);
        s += __shfl_down(s, 1);
        if (l16 == 0) unsafeAtomicAdd(&denom[m0 + rowL], s);
      }
    }
    __syncthreads();
#pragma unroll
    for (int j = 0; j < 8; ++j) {             // coalesced 16B stores
      const int cid = j * 256 + tid;
      const int row = cid >> 4, cc = cid & 15;
      bf16x8 v = *(const bf16x8*)&Es[row * 140 + cc * 8];
      *(bf16x8*)&Eg[(size_t)(m0 + row) * N + n0 + cc * 8] = v;
    }
  } else {
    // ================= val path: 64x64 tile, K=512 (gemm64 body) ===========
    constexpr int ASZ = 64 * 64;              // shorts per slot (8 KB)
    unsigned short* As = (unsigned short*)smem;
    unsigned short* Bs = As + 2 * ASZ;

    const int idx = lin - 2048;               // [0,512)
    const int n0 = (idx & 7) * 64;            // d-tile (512/64)
    const int m0 = (idx >> 3) * 64;           // n-tile (4096/64)

    f32x4 acc[4];
#pragma unroll
    for (int i = 0; i < 4; ++i) {
      f32x4 z = {0.f, 0.f, 0.f, 0.f};
      acc[i] = z;
    }

    const unsigned short* gA[2]; const unsigned short* gB[2]; int lc[2];
#pragma unroll
    for (int i = 0; i < 2; ++i) {
      const int c = tid + i * 256;
      const int row = c >> 3, col = ((c & 7) ^ (row & 7)) * 8;
      gA[i] = pb + (size_t)(m0 + row) * 512 + col;
      gB[i] = wvb + (size_t)(n0 + row) * 512 + col;
      lc[i] = c * 8;
    }

    auto issue = [&](int st, int kc) {
#pragma unroll
      for (int i = 0; i < 2; ++i) gl_lds16(gA[i] + kc, &As[st * ASZ + lc[i]]);
#pragma unroll
      for (int i = 0; i < 2; ++i) gl_lds16(gB[i] + kc, &Bs[st * ASZ + lc[i]]);
    };

    issue(0, 0);
    int cur = 0;
#pragma unroll 1
    for (int it = 0; it < 8; ++it) {          // BK=64, nk=8
      __builtin_amdgcn_s_barrier();
      if (it < 7) {
        issue(cur ^ 1, (it + 1) << 6);
        __builtin_amdgcn_s_waitcnt(0x0F74);
      } else {
        __builtin_amdgcn_s_waitcnt(0x0F70);
      }
      __builtin_amdgcn_s_barrier();

#pragma unroll
      for (int ks = 0; ks < 2; ++ks) {
        bf16x8 af[4], bfr;
#pragma unroll
        for (int mi = 0; mi < 4; ++mi) {
          const int r = mi * 16 + l16;
          af[mi] = *(const bf16x8*)&As[cur * ASZ + r * 64 + (((ks * 4 + quad) ^ (r & 7)) * 8)];
        }
        {
          const int r = wv * 16 + l16;
          bfr = *(const bf16x8*)&Bs[cur * ASZ + r * 64 + (((ks * 4 + quad) ^ (r & 7)) * 8)];
        }
#pragma unroll
        for (int mi = 0; mi < 4; ++mi)
          acc[mi] = MFMA(af[mi], bfr, acc[mi], 0, 0, 0);
      }
      cur ^= 1;
    }

#pragma unroll
    for (int mi = 0; mi < 4; ++mi) {
#pragma unroll
      for (int r = 0; r < 4; ++r) {
        const int m = m0 + mi * 16 + quad * 4 + r;
        const int n = n0 + wv * 16 + l16;
        val[(size_t)m * 512 + n] = f2bf(acc[mi][r]);
      }
    }
  }
}

// ============ PV kernel v2: 512 threads, BM=128, BN(e)=128, BK=64 ==========
// part[z][m,e] = sum_{n in half z} E[m,n] v2T[e,n]
// vs R11 (256thr, BN=64, 1024 blocks, 3 blk/CU = 12 waves): e-tiles 8 -> 4
// halves the E re-read (staging 768 -> 512 MB), grid 512 = 2 blk/CU x 8
// waves = 16 waves/CU, serial convoy walls 2x32/2 = 32 (was 4x32/3 = 43).
// Same proven 128B-row chunk-XOR q^(r&7) (0 conflicts), same drain-style
// counted loop (L=4). 8 waves = 2m x 4e; wave tile 64 x 32.
__global__ __launch_bounds__(512, 4)
void gemm_pv(const unsigned short* __restrict__ A,   // E: [8192][4096] bf16
             const unsigned short* __restrict__ B,   // v2T: [512][4096] bf16
             unsigned short* __restrict__ part)      // [2][8192][512] bf16
{
  constexpr int NCOL = 4096, KC = 2048;
  constexpr int ASZ = 128 * 64;   // shorts per A slot (16 KB)
  constexpr int BSZ = 128 * 64;   // shorts per B slot (16 KB)
  __shared__ unsigned short smem[2 * (ASZ + BSZ)];   // 64 KB
  unsigned short* As = smem;
  unsigned short* Bs = smem + 2 * ASZ;

  const int tid  = threadIdx.x;
  const int lane = tid & 63;
  const int wv   = tid >> 6;
  const int l16  = lane & 15;
  const int quad = lane >> 4;
  const int wm   = (wv >> 2) * 64;    // 2 m-waves
  const int we   = (wv & 3) * 32;     // 4 e-waves

  const int lin = blockIdx.x;                 // 512 blocks
  const int xcd = lin & 7, i = lin >> 3;      // i in [0,64)
  const int yt  = xcd * 8 + (i & 7);          // m-tile octet pinned to XCD
  const int combo = i >> 3;                   // 0..7
  const int et  = combo & 3;                  // e-tile (4 x 128)
  const int zt  = combo >> 2;                 // K half
  const int m0  = yt * 128;
  const int e0  = et * 128;
  const int kbeg = zt * KC;

  f32x4 acc[4][2];
#pragma unroll
  for (int a = 0; a < 4; ++a)
#pragma unroll
    for (int b = 0; b < 2; ++b) {
      f32x4 z = {0.f, 0.f, 0.f, 0.f};
      acc[a][b] = z;
    }

  // staging (128B rows = 8 chunks of 16B; chunk q of row r at q^(r&7)):
  // A: c = tid + j*512 in [0,1024): row=c>>3 (0..127); B same for e-rows.
  const unsigned short* gA[2]; int lA[2];
  const unsigned short* gB[2]; int lB[2];
#pragma unroll
  for (int j = 0; j < 2; ++j) {
    const int c = tid + j * 512;
    const int row = c >> 3, col = ((c & 7) ^ (row & 7)) * 8;
    gA[j] = A + (size_t)(m0 + row) * NCOL + col + kbeg;
    lA[j] = c * 8;
    gB[j] = B + (size_t)(e0 + row) * NCOL + col + kbeg;
    lB[j] = c * 8;
  }

  auto issue = [&](int st, int kc) {
#pragma unroll
    for (int j = 0; j < 2; ++j) gl_lds16(gA[j] + kc, &As[st * ASZ + lA[j]]);
#pragma unroll
    for (int j = 0; j < 2; ++j) gl_lds16(gB[j] + kc, &Bs[st * BSZ + lB[j]]);
  };

  issue(0, 0);
  int cur = 0;
#pragma unroll 1
  for (int it = 0; it < 32; ++it) {           // BK=64, nk=32
    __builtin_amdgcn_s_barrier();
    if (it < 31) {
      issue(cur ^ 1, (it + 1) * 64);
      __builtin_amdgcn_s_waitcnt(0x0F74);     // my 4 landed; next 4 in flight
    } else {
      __builtin_amdgcn_s_waitcnt(0x0F70);
    }
    __builtin_amdgcn_s_barrier();

    __builtin_amdgcn_s_setprio(1);
#pragma unroll
    for (int ks = 0; ks < 2; ++ks) {
      bf16x8 af[4], bfr[2];
#pragma unroll
      for (int mi = 0; mi < 4; ++mi) {
        const int r = wm + mi * 16 + l16;
        af[mi] = *(const bf16x8*)&As[cur * ASZ + r * 64 + (((ks * 4 + quad) ^ (r & 7)) * 8)];
      }
#pragma unroll
      for (int ni = 0; ni < 2; ++ni) {
        const int r = we + ni * 16 + l16;
        bfr[ni] = *(const bf16x8*)&Bs[cur * BSZ + r * 64 + (((ks * 4 + quad) ^ (r & 7)) * 8)];
      }
#pragma unroll
      for (int mi = 0; mi < 4; ++mi)
#pragma unroll
        for (int ni = 0; ni < 2; ++ni)
          acc[mi][ni] = MFMA(af[mi], bfr[ni], acc[mi][ni], 0, 0, 0);
    }
    __builtin_amdgcn_s_setprio(0);
    cur ^= 1;
  }

  unsigned short* Pz = part + (size_t)zt * (8192ull * 512);
#pragma unroll
  for (int mi = 0; mi < 4; ++mi) {
#pragma unroll
    for (int r = 0; r < 4; ++r) {
      const int m = m0 + wm + mi * 16 + quad * 4 + r;
#pragma unroll
      for (int ni = 0; ni < 2; ++ni) {
        const int e = e0 + we + ni * 16 + l16;
        Pz[(size_t)m * 512 + e] = f2bf(acc[mi][ni][r]);
      }
    }
  }
}

// ============ 64x64-tile GEMM (v2T launch) =================================
__global__ __launch_bounds__(256, 4)
void gemm64(const unsigned short* __restrict__ A,
            const unsigned short* __restrict__ B,
            unsigned short* __restrict__ C,
            int M, int N, int K)
{
  constexpr int ASZ = 64 * 64;    // shorts per slot (8 KB)
  __shared__ unsigned short smem[4 * ASZ];    // A0 A1 B0 B1 = 32 KB
  unsigned short* As = smem;
  unsigned short* Bs = smem + 2 * ASZ;

  const int tid  = threadIdx.x;
  const int lane = tid & 63;
  const int wv   = tid >> 6;
  const int l16  = lane & 15;
  const int quad = lane >> 4;

  const int n0 = blockIdx.x * 64;
  const int m0 = blockIdx.y * 64;

  f32x4 acc[4];
#pragma unroll
  for (int i = 0; i < 4; ++i) {
    f32x4 z = {0.f, 0.f, 0.f, 0.f};
    acc[i] = z;
  }

  const unsigned short* gA[2]; const unsigned short* gB[2]; int lc[2];
#pragma unroll
  for (int i = 0; i < 2; ++i) {
    const int c = tid + i * 256;
    const int row = c >> 3, col = ((c & 7) ^ (row & 7)) * 8;
    gA[i] = A + (size_t)(m0 + row) * K + col;
    gB[i] = B + (size_t)(n0 + row) * K + col;
    lc[i] = c * 8;
  }

  auto issue = [&](int st, int kc) {
#pragma unroll
    for (int i = 0; i < 2; ++i) gl_lds16(gA[i] + kc, &As[st * ASZ + lc[i]]);
#pragma unroll
    for (int i = 0; i < 2; ++i) gl_lds16(gB[i] + kc, &Bs[st * ASZ + lc[i]]);
  };

  const int nk = K >> 6;
  issue(0, 0);
  int cur = 0;
#pragma unroll 1
  for (int it = 0; it < nk; ++it) {
    __builtin_amdgcn_s_barrier();
    if (it + 1 < nk) {
      issue(cur ^ 1, (it + 1) << 6);
      __builtin_amdgcn_s_waitcnt(0x0F74);
    } else {
      __builtin_amdgcn_s_waitcnt(0x0F70);
    }
    __builtin_amdgcn_s_barrier();

#pragma unroll
    for (int ks = 0; ks < 2; ++ks) {
      bf16x8 af[4], bfr;
#pragma unroll
      for (int mi = 0; mi < 4; ++mi) {
        const int r = mi * 16 + l16;
        af[mi] = *(const bf16x8*)&As[cur * ASZ + r * 64 + (((ks * 4 + quad) ^ (r & 7)) * 8)];
      }
      {
        const int r = wv * 16 + l16;
        bfr = *(const bf16x8*)&Bs[cur * ASZ + r * 64 + (((ks * 4 + quad) ^ (r & 7)) * 8)];
      }
#pragma unroll
      for (int mi = 0; mi < 4; ++mi)
        acc[mi] = MFMA(af[mi], bfr, acc[mi], 0, 0, 0);
    }
    cur ^= 1;
  }

#pragma unroll
  for (int mi = 0; mi < 4; ++mi) {
#pragma unroll
    for (int r = 0; r < 4; ++r) {
      const int m = m0 + mi * 16 + quad * 4 + r;
      const int n = n0 + wv * 16 + l16;
      C[(size_t)m * N + n] = f2bf(acc[mi][r]);
    }
  }
}

// ===== prep_all: conversions/norms/bias in ONE launch (3456 blocks) =====
__global__ void prep_all(const float* __restrict__ x, const float* __restrict__ positions,
                         const float* __restrict__ w_v, const float* __restrict__ w_o,
                         const float* __restrict__ b_v, const float* __restrict__ b_o,
                         unsigned char* __restrict__ xq, unsigned char* __restrict__ pq,
                         unsigned short* __restrict__ pb,
                         unsigned short* __restrict__ wvb, unsigned short* __restrict__ wob,
                         float* __restrict__ x2, float* __restrict__ p2,
                         float* __restrict__ bias2, float* __restrict__ denom)
{
  const int b = blockIdx.x;
  const int tid = threadIdx.x;
  const int lane = tid & 63;
  const int wv = tid >> 6;

  if (b < 3072) {
    const bool isx = (b < 2048);
    const int r = (isx ? b : b - 2048) * 4 + wv;
    const float* X = isx ? x : positions;
    const float4* row = (const float4*)(X + (size_t)r * 512);
    const float4 a = row[lane];
    const float4 c = row[lane + 64];
    int wa = __builtin_amdgcn_cvt_pk_fp8_f32(a.x, a.y, 0, false);
    wa = __builtin_amdgcn_cvt_pk_fp8_f32(a.z, a.w, wa, true);
    int wc = __builtin_amdgcn_cvt_pk_fp8_f32(c.x, c.y, 0, false);
    wc = __builtin_amdgcn_cvt_pk_fp8_f32(c.z, c.w, wc, true);
    unsigned int* Q = (unsigned int*)(isx ? xq : pq) + (size_t)r * 128;
    Q[lane] = (unsigned int)wa;
    Q[lane + 64] = (unsigned int)wc;
    if (!isx) {                               // bf16 p kept for the val-GEMM
      ushort4 ua, uc;
      ua.x = f2bf(a.x); ua.y = f2bf(a.y); ua.z = f2bf(a.z); ua.w = f2bf(a.w);
      uc.x = f2bf(c.x); uc.y = f2bf(c.y); uc.z = f2bf(c.z); uc.w = f2bf(c.w);
      ushort4* orow = (ushort4*)(pb + (size_t)r * 512);
      orow[lane] = ua;
      orow[lane + 64] = uc;
    }
    float s = a.x*a.x + a.y*a.y + a.z*a.z + a.w*a.w
            + c.x*c.x + c.y*c.y + c.z*c.z + c.w*c.w;
#pragma unroll
    for (int off = 32; off > 0; off >>= 1) s += __shfl_down(s, off, 64);
    if (lane == 0) {
      if (isx) { x2[r] = s; denom[r] = 0.f; }
      else     { p2[r] = s; }
    }
  } else if (b < 3328) {
    const int i = (b - 3072) * 256 + tid;   // 65536 float4 each
    float4 a = ((const float4*)w_v)[i];
    float4 c = ((const float4*)w_o)[i];
    ushort4 ua, uc;
    ua.x = f2bf(a.x); ua.y = f2bf(a.y); ua.z = f2bf(a.z); ua.w = f2bf(a.w);
    uc.x = f2bf(c.x); uc.y = f2bf(c.y); uc.z = f2bf(c.z); uc.w = f2bf(c.w);
    ((ushort4*)wvb)[i] = ua;
    ((ushort4*)wob)[i] = uc;
  } else {
    const int e = (b - 3328) * 4 + wv;
    float s = 0.f;
#pragma unroll
    for (int j = 0; j < 8; ++j)
      s += w_o[(size_t)e * 512 + lane + j * 64] * b_v[lane + j * 64];
#pragma unroll
    for (int off = 32; off > 0; off >>= 1) s += __shfl_down(s, off, 64);
    if (lane == 0) bias2[e] = b_o[e] + s;   // softmax rows sum to 1
  }
}

// out[m,e] = (P0[m,e] + P1[m,e]) / denom[m] + bias2[e]   (P bf16, out fp32)
__global__ void reduce_out(const unsigned short* __restrict__ P,
                           const float* __restrict__ denom,
                           const float* __restrict__ bias2,
                           float* __restrict__ out) {
  const int i = blockIdx.x * 256 + threadIdx.x;   // 1,048,576 float4s
  const int m = i >> 7;
  const float rd = 1.0f / denom[m];
  const float4 b4 = ((const float4*)bias2)[i & 127];
  const ushort4 p0 = ((const ushort4*)P)[i];
  const ushort4 p1 = ((const ushort4*)P)[i + 1048576];
  float4 o;
  o.x = (bf2f(p0.x) + bf2f(p1.x)) * rd + b4.x;
  o.y = (bf2f(p0.y) + bf2f(p1.y)) * rd + b4.y;
  o.z = (bf2f(p0.z) + bf2f(p1.z)) * rd + b4.z;
  o.w = (bf2f(p0.w) + bf2f(p1.w)) * rd + b4.w;
  ((float4*)out)[i] = o;
}

extern "C" void kernel_launch(void* const* d_in, const int* in_sizes, int n_in,
                              void* d_out, int out_size, void* d_ws, size_t ws_size,
                              hipStream_t stream) {
  const float* x         = (const float*)d_in[0];
  const float* positions = (const float*)d_in[1];
  const float* scale     = (const float*)d_in[2];
  const float* w_v       = (const float*)d_in[3];
  const float* b_v       = (const float*)d_in[4];
  const float* w_o       = (const float*)d_in[5];
  const float* b_o       = (const float*)d_in[6];
  float* out = (float*)d_out;

  char* base = (char*)d_ws;
  unsigned short* Eb    = (unsigned short*)(base + 0);          // 64 MB [E .. PV]
  unsigned short* v2T   = (unsigned short*)(base + 67108864);   // 4 MB
  float*          denom = (float*)(base + 71303168);            // 32 KB
  float*          x2    = (float*)(base + 71335936);            // 32 KB
  float*          p2    = (float*)(base + 71368704);            // 16 KB
  float*          bias2 = (float*)(base + 71385088);            // 2 KB
  char* base2 = base + 71387136;
  unsigned short* part  = (unsigned short*)base2;               // 16 MB [PV .. reduce]
  unsigned char*  xq    = (unsigned char*)base2;                // 4 MB  [prep .. E]
  unsigned char*  pq    = (unsigned char*)(base2 + 4194304);    // 2 MB  [prep .. E]
  unsigned short* pb    = (unsigned short*)(base2 + 6291456);   // 4 MB  [prep .. val]
  unsigned short* wvb   = (unsigned short*)(base2 + 10485760);  // 0.5 MB
  unsigned short* wo_b  = (unsigned short*)(base2 + 11010048);  // 0.5 MB
  unsigned short* val2  = (unsigned short*)(base2 + 11534336);  // 4 MB [merged .. v2T]

  // all prep in one launch
  prep_all<<<3456, 256, 0, stream>>>(x, positions, w_v, w_o, b_v, b_o,
                                     xq, pq, pb, wvb, wo_b, x2, p2, bias2, denom);

  // merged: E[m,n]=exp(scale/(dist+0.1)) + denom  ||  val = pb . wvb^T
  f8_and_val<0><<<2560, 256, 0, stream>>>(xq, pq, Eb, x2, p2, scale, denom,
                                          pb, wvb, val2);

  // v2T[e,n] = sum_d wo[e,d] val[n,d]   (512 blocks of 64x64)
  gemm64<<<dim3(64, 8), 256, 0, stream>>>(wo_b, val2, v2T, 512, 4096, 512);

  // part[z][m,e] = sum_{n in half z} E[m,n] v2T[e,n]
  // 512 blocks x 512 thr: BM=128, BN(e)=128, BK=64, 64KB LDS, 16 waves/CU
  gemm_pv<<<512, 512, 0, stream>>>(Eb, v2T, part);

  // out = (part0 + part1)/denom + bias2
  reduce_out<<<4096, 256, 0, stream>>>(part, denom, bias2, out);
}